// Round 12
// baseline (941.782 us; speedup 1.0000x reference)
//
#include <hip/hip_runtime.h>
#include <hip/hip_bf16.h>
#include <math.h>

#define B_ 8
#define S_ 1024
#define F_ 75
#define D_ 128
#define INNER_ 256
#define NH_ 4
#define DH_ 64
#define MROWS_ (B_*S_)   // 8192

static __device__ __forceinline__ float frcp(float x){ return __builtin_amdgcn_rcpf(x); }
static __device__ __forceinline__ float fsigm(float x){ return frcp(1.0f + __expf(-x)); }
static __device__ __forceinline__ float flogsig(float x){
    return fminf(x, 0.f) - __logf(1.0f + __expf(-fabsf(x)));
}
static __device__ __forceinline__ float ftanh(float z){
    return 1.0f - 2.0f*frcp(__expf(2.0f*z) + 1.0f);
}

// ---------------- Tiled GEMM: C = A @ W^T + bias (+ res) ----------------
__global__ __launch_bounds__(256, 2) void gemm_bias_big(
        const float* __restrict__ A, const float* __restrict__ W,
        const float* __restrict__ bias, const float* __restrict__ res,
        float* __restrict__ C, int M, int N, int K) {
    __shared__ float As[64*68];
    __shared__ float Ws[64*68];
    int tid = threadIdx.x;
    int wid = tid >> 6, lane = tid & 63;
    int wy = wid >> 1, wx = wid & 1;
    int sg = lane >> 3, tg = lane & 7;
    int m0 = blockIdx.y*64, n0 = blockIdx.x*64;
    int r = tid >> 2, c0 = (tid & 3) << 4;
    bool vec = ((K & 3) == 0);
    float acc[4][4];
    #pragma unroll
    for (int i = 0; i < 4; ++i)
        #pragma unroll
        for (int j = 0; j < 4; ++j) acc[i][j] = 0.f;

    for (int k0 = 0; k0 < K; k0 += 64) {
        __syncthreads();
        const float* Ar = A + (size_t)(m0+r)*K + k0;
        const float* Wr = W + (size_t)(n0+r)*K + k0;
        if (vec) {
            #pragma unroll
            for (int i = 0; i < 4; ++i) {
                *(float4*)(&As[r*68 + c0 + 4*i]) = *(const float4*)(Ar + c0 + 4*i);
                *(float4*)(&Ws[r*68 + c0 + 4*i]) = *(const float4*)(Wr + c0 + 4*i);
            }
        } else {
            #pragma unroll
            for (int i = 0; i < 4; ++i)
                #pragma unroll
                for (int e = 0; e < 4; ++e) {
                    int c = c0 + 4*i + e;
                    bool ok = (k0 + c) < K;
                    As[r*68 + c] = ok ? Ar[c] : 0.f;
                    Ws[r*68 + c] = ok ? Wr[c] : 0.f;
                }
        }
        __syncthreads();
        const float* arow = &As[(32*wy + sg)*68];
        const float* brow = &Ws[(32*wx + tg)*68];
        #pragma unroll 2
        for (int d = 0; d < 64; d += 4) {
            float4 b0 = *(const float4*)(brow + 0*544 + d);
            float4 b1 = *(const float4*)(brow + 1*544 + d);
            float4 b2 = *(const float4*)(brow + 2*544 + d);
            float4 b3 = *(const float4*)(brow + 3*544 + d);
            #pragma unroll
            for (int i = 0; i < 4; ++i) {
                float4 a = *(const float4*)(arow + i*544 + d);
                acc[i][0] += a.x*b0.x + a.y*b0.y + a.z*b0.z + a.w*b0.w;
                acc[i][1] += a.x*b1.x + a.y*b1.y + a.z*b1.z + a.w*b1.w;
                acc[i][2] += a.x*b2.x + a.y*b2.y + a.z*b2.z + a.w*b2.w;
                acc[i][3] += a.x*b3.x + a.y*b3.y + a.z*b3.z + a.w*b3.w;
            }
        }
    }
    #pragma unroll
    for (int i = 0; i < 4; ++i) {
        int m = m0 + 32*wy + 8*i + sg;
        #pragma unroll
        for (int j = 0; j < 4; ++j) {
            int n = n0 + 32*wx + 8*j + tg;
            float v = acc[i][j] + bias[n];
            if (res) v += res[(size_t)m*N + n];
            C[(size_t)m*N + n] = v;
        }
    }
}

// ---------------- FUSED GEMM (N=128) + LayerNorm epilogue ----------------
// One block owns 64 full rows (all 128 cols): acc 4x8 per lane (cols 64*wx+8j+tg).
// Epilogue: row sums via tg-butterfly + LDS cross-wave combine, then writes
// H = gemm(+res) and Rout = LN(H)*lnw. Replaces gemm + ln_kernel pair.
__global__ __launch_bounds__(256, 2) void gemm_ln(
        const float* __restrict__ A, const float* __restrict__ W,
        const float* __restrict__ bias, const float* __restrict__ res,
        const float* __restrict__ lnw, float* __restrict__ H,
        float* __restrict__ Rout, int M, int K) {
    __shared__ float As[64*68];
    __shared__ float Ws[128*68];
    __shared__ float Lsum[2][64], Lssq[2][64];
    int tid = threadIdx.x;
    int wid = tid >> 6, lane = tid & 63;
    int wy = wid >> 1, wx = wid & 1;
    int sg = lane >> 3, tg = lane & 7;
    int m0 = blockIdx.x*64;
    int r = tid >> 2, c0 = (tid & 3) << 4;     // A staging
    int rw = tid >> 1, cw0 = (tid & 1) << 5;   // W staging (128 rows, 32 floats)
    bool vec = ((K & 3) == 0);
    float acc[4][8];
    #pragma unroll
    for (int i = 0; i < 4; ++i)
        #pragma unroll
        for (int j = 0; j < 8; ++j) acc[i][j] = 0.f;

    for (int k0 = 0; k0 < K; k0 += 64) {
        __syncthreads();
        const float* Ar = A + (size_t)(m0+r)*K + k0;
        const float* Wr = W + (size_t)rw*K + k0;
        if (vec) {
            #pragma unroll
            for (int i = 0; i < 4; ++i)
                *(float4*)(&As[r*68 + c0 + 4*i]) = *(const float4*)(Ar + c0 + 4*i);
            #pragma unroll
            for (int i = 0; i < 8; ++i)
                *(float4*)(&Ws[rw*68 + cw0 + 4*i]) = *(const float4*)(Wr + cw0 + 4*i);
        } else {
            #pragma unroll
            for (int i = 0; i < 4; ++i)
                #pragma unroll
                for (int e = 0; e < 4; ++e) {
                    int c = c0 + 4*i + e;
                    As[r*68 + c] = ((k0 + c) < K) ? Ar[c] : 0.f;
                }
            #pragma unroll
            for (int i = 0; i < 8; ++i)
                #pragma unroll
                for (int e = 0; e < 4; ++e) {
                    int c = cw0 + 4*i + e;
                    Ws[rw*68 + c] = ((k0 + c) < K) ? Wr[c] : 0.f;
                }
        }
        __syncthreads();
        const float* arow = &As[(32*wy + sg)*68];
        const float* brow = &Ws[(64*wx + tg)*68];
        #pragma unroll 1
        for (int d = 0; d < 64; d += 4) {
            float4 bv[8];
            #pragma unroll
            for (int j = 0; j < 8; ++j)
                bv[j] = *(const float4*)(brow + j*544 + d);
            #pragma unroll
            for (int i = 0; i < 4; ++i) {
                float4 a = *(const float4*)(arow + i*544 + d);
                #pragma unroll
                for (int j = 0; j < 8; ++j)
                    acc[i][j] += a.x*bv[j].x + a.y*bv[j].y + a.z*bv[j].z + a.w*bv[j].w;
            }
        }
    }
    // epilogue: finish values + per-row sum/sumsq
    float ps[4], pss[4];
    #pragma unroll
    for (int i = 0; i < 4; ++i) {
        int m = m0 + 32*wy + 8*i + sg;
        float s = 0.f, ss = 0.f;
        #pragma unroll
        for (int j = 0; j < 8; ++j) {
            int n = 64*wx + 8*j + tg;
            float vv = acc[i][j] + bias[n];
            if (res) vv += res[(size_t)m*128 + n];
            acc[i][j] = vv;
            s += vv; ss += vv*vv;
        }
        ps[i] = s; pss[i] = ss;
    }
    #pragma unroll
    for (int bm = 1; bm <= 4; bm <<= 1)
        #pragma unroll
        for (int i = 0; i < 4; ++i) {
            ps[i]  += __shfl_xor(ps[i],  bm, 64);
            pss[i] += __shfl_xor(pss[i], bm, 64);
        }
    if (tg == 0) {
        #pragma unroll
        for (int i = 0; i < 4; ++i) {
            int rloc = 32*wy + 8*i + sg;
            Lsum[wx][rloc] = ps[i];
            Lssq[wx][rloc] = pss[i];
        }
    }
    __syncthreads();
    #pragma unroll
    for (int i = 0; i < 4; ++i) {
        int rloc = 32*wy + 8*i + sg;
        int m = m0 + rloc;
        float s  = Lsum[0][rloc] + Lsum[1][rloc];
        float ss = Lssq[0][rloc] + Lssq[1][rloc];
        float mu = s*(1.f/128.f);
        float var = ss*(1.f/128.f) - mu*mu;
        float inv = rsqrtf(var + 1e-5f);
        #pragma unroll
        for (int j = 0; j < 8; ++j) {
            int n = 64*wx + 8*j + tg;
            float vv = acc[i][j];
            H[(size_t)m*128 + n]    = vv;
            Rout[(size_t)m*128 + n] = (vv-mu)*inv*lnw[n];
        }
    }
}

// ---------------- FUSED FFN up-GEMM + gelu(g)*u2 epilogue ----------------
// Block (bx, by): A rows by*64, g cols = bx*64 + tile, u2 cols = 192 + same.
// Stages one A tile and BOTH W tiles; writes act directly (u never materialized).
__global__ __launch_bounds__(256, 2) void gemm_ffn_act(
        const float* __restrict__ A, const float* __restrict__ Wu,
        const float* __restrict__ bu, float* __restrict__ act, int M) {
    __shared__ float As[64*68];
    __shared__ float Wg[64*68];
    __shared__ float Wu2[64*68];
    int tid = threadIdx.x;
    int wid = tid >> 6, lane = tid & 63;
    int wy = wid >> 1, wx = wid & 1;
    int sg = lane >> 3, tg = lane & 7;
    int m0 = blockIdx.y*64, nb = blockIdx.x*64;
    int r = tid >> 2, c0 = (tid & 3) << 4;
    float ag[4][4], au[4][4];
    #pragma unroll
    for (int i = 0; i < 4; ++i)
        #pragma unroll
        for (int j = 0; j < 4; ++j) { ag[i][j] = 0.f; au[i][j] = 0.f; }

    for (int k0 = 0; k0 < 128; k0 += 64) {
        __syncthreads();
        const float* Ar = A + (size_t)(m0+r)*128 + k0;
        const float* Wgr = Wu + (size_t)(nb+r)*128 + k0;
        const float* Wur = Wu + (size_t)(192+nb+r)*128 + k0;
        #pragma unroll
        for (int i = 0; i < 4; ++i) {
            *(float4*)(&As[r*68 + c0 + 4*i])  = *(const float4*)(Ar + c0 + 4*i);
            *(float4*)(&Wg[r*68 + c0 + 4*i])  = *(const float4*)(Wgr + c0 + 4*i);
            *(float4*)(&Wu2[r*68 + c0 + 4*i]) = *(const float4*)(Wur + c0 + 4*i);
        }
        __syncthreads();
        const float* arow = &As[(32*wy + sg)*68];
        const float* grow = &Wg[(32*wx + tg)*68];
        const float* urow = &Wu2[(32*wx + tg)*68];
        #pragma unroll 2
        for (int d = 0; d < 64; d += 4) {
            float4 g0 = *(const float4*)(grow + 0*544 + d);
            float4 g1 = *(const float4*)(grow + 1*544 + d);
            float4 g2 = *(const float4*)(grow + 2*544 + d);
            float4 g3 = *(const float4*)(grow + 3*544 + d);
            float4 u0 = *(const float4*)(urow + 0*544 + d);
            float4 u1 = *(const float4*)(urow + 1*544 + d);
            float4 u2 = *(const float4*)(urow + 2*544 + d);
            float4 u3 = *(const float4*)(urow + 3*544 + d);
            #pragma unroll
            for (int i = 0; i < 4; ++i) {
                float4 a = *(const float4*)(arow + i*544 + d);
                ag[i][0] += a.x*g0.x + a.y*g0.y + a.z*g0.z + a.w*g0.w;
                ag[i][1] += a.x*g1.x + a.y*g1.y + a.z*g1.z + a.w*g1.w;
                ag[i][2] += a.x*g2.x + a.y*g2.y + a.z*g2.z + a.w*g2.w;
                ag[i][3] += a.x*g3.x + a.y*g3.y + a.z*g3.z + a.w*g3.w;
                au[i][0] += a.x*u0.x + a.y*u0.y + a.z*u0.z + a.w*u0.w;
                au[i][1] += a.x*u1.x + a.y*u1.y + a.z*u1.z + a.w*u1.w;
                au[i][2] += a.x*u2.x + a.y*u2.y + a.z*u2.z + a.w*u2.w;
                au[i][3] += a.x*u3.x + a.y*u3.y + a.z*u3.z + a.w*u3.w;
            }
        }
    }
    #pragma unroll
    for (int i = 0; i < 4; ++i) {
        int m = m0 + 32*wy + 8*i + sg;
        #pragma unroll
        for (int j = 0; j < 4; ++j) {
            int n = nb + 32*wx + 8*j + tg;
            float g  = ag[i][j] + bu[n];
            float u2 = au[i][j] + bu[192+n];
            float ge = 0.5f*g*(1.0f + erff(g*0.70710678118f));
            act[(size_t)m*192 + n] = ge*u2;
        }
    }
}

// ---------------- FUSED mLSTM front-end: conv+silu, q/k/v headwise, gateproj ----------------
__global__ __launch_bounds__(64) void mlstm_qkv(
        const float* __restrict__ up, const float* __restrict__ convk,
        const float* __restrict__ convb,
        const float* __restrict__ Wq, const float* __restrict__ bq,
        const float* __restrict__ Wk, const float* __restrict__ bk,
        const float* __restrict__ Wv, const float* __restrict__ bv,
        const float* __restrict__ Wig, const float* __restrict__ big,
        const float* __restrict__ Wfg, const float* __restrict__ bfg,
        float* __restrict__ xc, float* __restrict__ q, float* __restrict__ k,
        float* __restrict__ v, float* __restrict__ igp, float* __restrict__ fgp) {
    int row = blockIdx.x;
    int b = row >> 10, s = row & 1023;
    int l = threadIdx.x;
    int c0 = l*4;
    float4 xm[4];
    #pragma unroll
    for (int i = 0; i < 4; ++i) {
        int sp = s - 3 + i;
        if (sp >= 0) xm[i] = *(const float4*)(up + (size_t)(row-3+i)*512 + c0);
        else         xm[i] = make_float4(0.f,0.f,0.f,0.f);
    }
    float xcv[4];
    #pragma unroll
    for (int j = 0; j < 4; ++j) {
        int c = c0 + j;
        float acc = convb[c];
        #pragma unroll
        for (int i = 0; i < 4; ++i)
            acc += ((const float*)&xm[i])[j] * convk[c*4+i];
        xcv[j] = acc * fsigm(acc);
    }
    *(float4*)(xc + (size_t)row*256 + c0) = make_float4(xcv[0],xcv[1],xcv[2],xcv[3]);
    float qv[4], kv[4], vv[4];
    #pragma unroll
    for (int o = 0; o < 4; ++o) {
        const float* wq = Wq + ((size_t)l*4 + o)*4;
        const float* wk = Wk + ((size_t)l*4 + o)*4;
        const float* wv = Wv + ((size_t)l*4 + o)*4;
        float aq = bq[c0+o], ak = bk[c0+o], avv = bv[c0+o];
        #pragma unroll
        for (int i = 0; i < 4; ++i) {
            aq  += xcv[i]*wq[i];
            ak  += xcv[i]*wk[i];
            avv += ((const float*)&xm[3])[i]*wv[i];
        }
        qv[o]=aq; kv[o]=ak; vv[o]=avv;
    }
    *(float4*)(q + (size_t)row*256 + c0) = make_float4(qv[0],qv[1],qv[2],qv[3]);
    *(float4*)(k + (size_t)row*256 + c0) = make_float4(kv[0],kv[1],kv[2],kv[3]);
    *(float4*)(v + (size_t)row*256 + c0) = make_float4(vv[0],vv[1],vv[2],vv[3]);
    float dots[8];
    #pragma unroll
    for (int g = 0; g < 4; ++g) {
        float di = 0.f, df = 0.f;
        #pragma unroll
        for (int j = 0; j < 4; ++j) {
            di += qv[j]*Wig[g*768 + c0 + j] + kv[j]*Wig[g*768 + 256 + c0 + j]
                + vv[j]*Wig[g*768 + 512 + c0 + j];
            df += qv[j]*Wfg[g*768 + c0 + j] + kv[j]*Wfg[g*768 + 256 + c0 + j]
                + vv[j]*Wfg[g*768 + 512 + c0 + j];
        }
        dots[g] = di; dots[4+g] = df;
    }
    #pragma unroll
    for (int off = 32; off > 0; off >>= 1)
        #pragma unroll
        for (int g = 0; g < 8; ++g) dots[g] += __shfl_down(dots[g], off, 64);
    if (l == 0) {
        #pragma unroll
        for (int g = 0; g < 4; ++g) {
            igp[((size_t)b*NH_+g)*S_ + s] = dots[g]   + big[g];
            fgp[((size_t)b*NH_+g)*S_ + s] = dots[4+g] + bfg[g];
        }
    }
}

// ---------------- FUSED sLSTM front-end: conv+silu + all-4-gate matvecs ----------------
__global__ __launch_bounds__(128) void slstm_convgates(
        const float* __restrict__ r, const float* __restrict__ convk,
        const float* __restrict__ convb, const float* __restrict__ Wi,
        const float* __restrict__ Wf, const float* __restrict__ Wz,
        const float* __restrict__ Wo, float* __restrict__ GX) {
    int row = blockIdx.x; int s = row & 1023;
    int c = threadIdx.x;
    __shared__ float rcL[128], rL[128];
    float rv = r[(size_t)row*128 + c];
    float acc = convb[c];
    #pragma unroll
    for (int i = 0; i < 4; ++i) {
        int sp = s - 3 + i;
        if (sp >= 0) acc += r[(size_t)(row-3+i)*128 + c]*convk[c*4+i];
    }
    float rcv = acc * fsigm(acc);
    rcL[c] = rcv; rL[c] = rv;
    __syncthreads();
    int h = c >> 5, o = c & 31;
    size_t wb = ((size_t)h*32 + o)*32;
    const float* rc_ = rcL + h*32;
    const float* rr_ = rL + h*32;
    float di=0.f, df=0.f, dz=0.f, doo=0.f;
    #pragma unroll
    for (int i = 0; i < 32; ++i) {
        float a = rc_[i], cc = rr_[i];
        di  += a*Wi[wb+i];
        df  += a*Wf[wb+i];
        dz  += cc*Wz[wb+i];
        doo += cc*Wo[wb+i];
    }
    float* g = GX + (size_t)row*512 + h*128 + o;
    g[0]  = di;
    g[32] = df;
    g[64] = dz;
    g[96] = doo;
}

// ---------------- mLSTM decay precompute ----------------
__global__ void mlstm_scan_pre(const float* __restrict__ igp, const float* __restrict__ fgp,
                               float* __restrict__ lc, float* __restrict__ av,
                               float* __restrict__ mx) {
    int bh = blockIdx.x; int t = threadIdx.x;  // 1024 threads
    __shared__ float buf[2][1024];
    float ls = flogsig(fgp[(size_t)bh*S_ + t]);
    int cur = 0;
    buf[0][t] = ls; __syncthreads();
    for (int off=1; off<1024; off<<=1) {
        float x2 = buf[cur][t];
        if (t >= off) x2 += buf[cur][t-off];
        buf[cur^1][t] = x2; cur ^= 1; __syncthreads();
    }
    float lcv = buf[cur][t];
    lc[(size_t)bh*S_+t] = lcv;
    float a = igp[(size_t)bh*S_+t] - lcv;
    av[(size_t)bh*S_+t] = a;
    __syncthreads();
    cur = 0; buf[0][t] = a; __syncthreads();
    for (int off=1; off<1024; off<<=1) {
        float x2 = buf[cur][t];
        if (t >= off) x2 = fmaxf(x2, buf[cur][t-off]);
        buf[cur^1][t] = x2; cur ^= 1; __syncthreads();
    }
    mx[(size_t)bh*S_+t] = buf[cur][t];
}

// ---------------- mLSTM attention: tiled flash-style ----------------
__global__ __launch_bounds__(256, 2) void mlstm_attn_tiled(
        const float* __restrict__ q, const float* __restrict__ k,
        const float* __restrict__ v, const float* __restrict__ lc,
        const float* __restrict__ av, const float* __restrict__ mx,
        float* __restrict__ hc) {
    int bid = blockIdx.x;
    int stile = 15 - (bid & 15);
    int bh = bid >> 4;
    int hh = bh & 3, b = bh >> 2;
    int s0 = stile << 6;
    int tid = threadIdx.x;
    int wid = tid >> 6, lane = tid & 63;
    int wy = wid >> 1, wx = wid & 1;
    int sg = lane >> 3, tg = lane & 7;

    __shared__ float qs[64*68];
    __shared__ float kst[64*68];
    __shared__ float vtT[64*68];
    __shared__ float avt[64], maxsL[64], normL[64], rsumL[128];

    const size_t bhS = (size_t)bh * S_;
    {
        int r = tid >> 2, c0 = (tid & 3) << 4;
        const float* qg = q + ((size_t)(b*S_) + s0 + r)*INNER_ + hh*64;
        #pragma unroll
        for (int i = 0; i < 4; ++i) {
            float4 t4 = *(const float4*)(qg + c0 + 4*i);
            float4 w4; w4.x=t4.x*0.125f; w4.y=t4.y*0.125f; w4.z=t4.z*0.125f; w4.w=t4.w*0.125f;
            *(float4*)(&qs[r*68 + c0 + 4*i]) = w4;
        }
        if (tid < 64) maxsL[tid] = lc[bhS + s0 + tid] + mx[bhS + s0 + tid];
    }
    float msv[4];
    #pragma unroll
    for (int i = 0; i < 4; ++i)
        msv[i] = mx[bhS + s0 + 32*wy + 8*i + sg];

    float O[4][4];
    float rsAcc[4];
    #pragma unroll
    for (int i = 0; i < 4; ++i) {
        rsAcc[i] = 0.f;
        #pragma unroll
        for (int j = 0; j < 4; ++j) O[i][j] = 0.f;
    }

    for (int t0 = 0; t0 <= s0; t0 += 64) {
        __syncthreads();
        {
            int r = tid >> 2, c0 = (tid & 3) << 4;
            const float* kg = k + ((size_t)(b*S_) + t0 + r)*INNER_ + hh*64;
            const float* vg = v + ((size_t)(b*S_) + t0 + r)*INNER_ + hh*64;
            #pragma unroll
            for (int i = 0; i < 4; ++i) {
                *(float4*)(&kst[r*68 + c0 + 4*i]) = *(const float4*)(kg + c0 + 4*i);
                float4 v4 = *(const float4*)(vg + c0 + 4*i);
                int dc = c0 + 4*i;
                vtT[(dc+0)*68 + r] = v4.x;
                vtT[(dc+1)*68 + r] = v4.y;
                vtT[(dc+2)*68 + r] = v4.z;
                vtT[(dc+3)*68 + r] = v4.w;
            }
            if (tid < 64) avt[tid] = av[bhS + t0 + tid];
        }
        __syncthreads();
        float dot[4][4];
        #pragma unroll
        for (int i = 0; i < 4; ++i)
            #pragma unroll
            for (int j = 0; j < 4; ++j) dot[i][j] = 0.f;
        {
            const float* qrow = &qs[(32*wy + sg)*68];
            const float* krow = &kst[(32*wx + tg)*68];
            #pragma unroll 2
            for (int d = 0; d < 64; d += 4) {
                float4 b0 = *(const float4*)(krow + 0*544 + d);
                float4 b1 = *(const float4*)(krow + 1*544 + d);
                float4 b2 = *(const float4*)(krow + 2*544 + d);
                float4 b3 = *(const float4*)(krow + 3*544 + d);
                #pragma unroll
                for (int i = 0; i < 4; ++i) {
                    float4 a = *(const float4*)(qrow + i*544 + d);
                    dot[i][0] += a.x*b0.x + a.y*b0.y + a.z*b0.z + a.w*b0.w;
                    dot[i][1] += a.x*b1.x + a.y*b1.y + a.z*b1.z + a.w*b1.w;
                    dot[i][2] += a.x*b2.x + a.y*b2.y + a.z*b2.z + a.w*b2.w;
                    dot[i][3] += a.x*b3.x + a.y*b3.y + a.z*b3.z + a.w*b3.w;
                }
            }
        }
        __syncthreads();
        #pragma unroll
        for (int i = 0; i < 4; ++i) {
            int s_loc = 32*wy + 8*i + sg;
            float rp = 0.f;
            #pragma unroll
            for (int j = 0; j < 4; ++j) {
                int t_loc = 32*wx + 8*j + tg;
                bool ok = (t0 + t_loc) <= (s0 + s_loc);
                float p = ok ? dot[i][j]*__expf(avt[t_loc] - msv[i]) : 0.f;
                kst[s_loc*68 + t_loc] = p;
                rp += p;
            }
            rp += __shfl_xor(rp, 1);
            rp += __shfl_xor(rp, 2);
            rp += __shfl_xor(rp, 4);
            rsAcc[i] += rp;
        }
        __syncthreads();
        {
            const float* prow = &kst[(32*wy + sg)*68];
            const float* vrow = &vtT[(32*wx + tg)*68];
            #pragma unroll 2
            for (int tt = 0; tt < 64; tt += 4) {
                float4 b0 = *(const float4*)(vrow + 0*544 + tt);
                float4 b1 = *(const float4*)(vrow + 1*544 + tt);
                float4 b2 = *(const float4*)(vrow + 2*544 + tt);
                float4 b3 = *(const float4*)(vrow + 3*544 + tt);
                #pragma unroll
                for (int i = 0; i < 4; ++i) {
                    float4 a = *(const float4*)(prow + i*544 + tt);
                    O[i][0] += a.x*b0.x + a.y*b0.y + a.z*b0.z + a.w*b0.w;
                    O[i][1] += a.x*b1.x + a.y*b1.y + a.z*b1.z + a.w*b1.w;
                    O[i][2] += a.x*b2.x + a.y*b2.y + a.z*b2.z + a.w*b2.w;
                    O[i][3] += a.x*b3.x + a.y*b3.y + a.z*b3.z + a.w*b3.w;
                }
            }
        }
    }
    if (tg == 0) {
        #pragma unroll
        for (int i = 0; i < 4; ++i)
            rsumL[wx*64 + 32*wy + 8*i + sg] = rsAcc[i];
    }
    __syncthreads();
    if (tid < 64) {
        float tot = rsumL[tid] + rsumL[64 + tid];
        normL[tid] = fmaxf(fabsf(tot), __expf(-maxsL[tid])) + 1e-6f;
    }
    __syncthreads();
    #pragma unroll
    for (int i = 0; i < 4; ++i) {
        int s_loc = 32*wy + 8*i + sg;
        float inv = 1.0f / normL[s_loc];
        #pragma unroll
        for (int j = 0; j < 4; ++j) {
            int d_loc = 32*wx + 8*j + tg;
            hc[((size_t)(b*S_) + s0 + s_loc)*INNER_ + hh*64 + d_loc] = O[i][j] * inv;
        }
    }
}

// ---------------- mLSTM output: multihead LN (GS=64) + skip + gate ----------------
__global__ void mlstm_out(const float* __restrict__ hc, const float* __restrict__ xc,
                          const float* __restrict__ up, const float* __restrict__ onw,
                          const float* __restrict__ skip, float* __restrict__ hs) {
    int row = blockIdx.x; int c = threadIdx.x;  // 256 threads
    float v = hc[(size_t)row*INNER_ + c];
    __shared__ float s1[256], s2[256];
    s1[c]=v; s2[c]=v*v; __syncthreads();
    int li = c & 63;
    for (int off=32; off>0; off>>=1){
        if (li < off){ s1[c]+=s1[c+off]; s2[c]+=s2[c+off]; }
        __syncthreads();
    }
    int base = c & ~63;
    float mu = s1[base]*(1.f/64.f);
    float var = s2[base]*(1.f/64.f) - mu*mu;
    float ht = (v-mu)*rsqrtf(var+1e-5f)*onw[c];
    float z = up[(size_t)row*512 + 256 + c];
    hs[(size_t)row*INNER_ + c] = (ht + skip[c]*xc[(size_t)row*INNER_+c]) * (z*fsigm(z));
}

// ---------------- sLSTM scan: pair-lane layout, DPP gate exchange ----------------
__global__ __launch_bounds__(64, 1) void slstm_scan_wave(
        const float* __restrict__ gx, const float* __restrict__ R,
        const float* __restrict__ bb, float* __restrict__ ys) {
    int blk = blockIdx.x; int hh = blk & 3; int b = blk >> 2;
    int l = threadIdx.x;  // 0..63
    int e = l >> 1, p = l & 1;
    int o0 = p*32 + e, o1 = (p+2)*32 + e;
    float Rc0[32], Rc1[32];
    #pragma unroll
    for (int d = 0; d < 32; ++d) {
        Rc0[d] = R[(size_t)(hh*32 + d)*128 + o0];
        Rc1[d] = R[(size_t)(hh*32 + d)*128 + o1];
        asm volatile("" : "+v"(Rc0[d]));
        asm volatile("" : "+v"(Rc1[d]));
    }
    float bj0 = bb[hh*128 + o0], bj1 = bb[hh*128 + o1];
    float cst = 0.f, nst = 0.f, mst = 0.f, y = 0.f;
    const float* gbase = gx + (size_t)(b*S_)*512 + hh*128;
    float* ybase = ys + (size_t)(b*S_)*128 + hh*32 + e;
    float ga[4], gb[4];
    #pragma unroll
    for (int u = 0; u < 4; ++u) {
        ga[u] = gbase[(size_t)u*512 + o0];
        gb[u] = gbase[(size_t)u*512 + o1];
    }
    for (int t = 0; t < S_; t += 4) {
        float gna[4], gnb[4];
        #pragma unroll
        for (int u = 0; u < 4; ++u) {
            int tn = t + 4 + u;
            size_t off = (size_t)(tn < S_ ? tn : 0) * 512;
            gna[u] = gbase[off + o0];
            gnb[u] = gbase[off + o1];
        }
        #pragma unroll
        for (int u = 0; u < 4; ++u) {
            float a0=0.f, a1=0.f, a2=0.f, a3=0.f;
            float c0=0.f, c1=0.f, c2=0.f, c3=0.f;
            #pragma unroll
            for (int d = 0; d < 32; d += 4) {
                float y0 = __int_as_float(__builtin_amdgcn_readlane(__float_as_int(y), 2*d));
                float y1 = __int_as_float(__builtin_amdgcn_readlane(__float_as_int(y), 2*d+2));
                float y2 = __int_as_float(__builtin_amdgcn_readlane(__float_as_int(y), 2*d+4));
                float y3 = __int_as_float(__builtin_amdgcn_readlane(__float_as_int(y), 2*d+6));
                a0 += y0*Rc0[d];   c0 += y0*Rc1[d];
                a1 += y1*Rc0[d+1]; c1 += y1*Rc1[d+1];
                a2 += y2*Rc0[d+2]; c2 += y2*Rc1[d+2];
                a3 += y3*Rc0[d+3]; c3 += y3*Rc1[d+3];
            }
            float r0 = ga[u] + bj0 + ((a0+a1)+(a2+a3));
            float r1 = gb[u] + bj1 + ((c0+c1)+(c2+c3));
            float fo0 = __int_as_float(__builtin_amdgcn_mov_dpp(__float_as_int(r0), 0xB1, 0xF, 0xF, true));
            float fo1 = __int_as_float(__builtin_amdgcn_mov_dpp(__float_as_int(r1), 0xB1, 0xF, 0xF, true));
            float iraw = p ? fo0 : r0;
            float fraw = p ? r0 : fo0;
            float zraw = p ? fo1 : r1;
            float oraw = p ? r1 : fo1;
            int t_abs = t + u;
            float lfm = mst + flogsig(fraw);
            float mnew = (t_abs == 0) ? iraw : fmaxf(iraw, lfm);
            float igv = __expf(iraw - mnew), fgv = __expf(lfm - mnew);
            cst = fgv*cst + igv*ftanh(zraw);
            nst = fgv*nst + igv;
            mst = mnew;
            y = cst * frcp(nst * (1.0f + __expf(-oraw)));
            if (p == 0) ybase[(size_t)t_abs*128] = y;
        }
        #pragma unroll
        for (int u = 0; u < 4; ++u) { ga[u] = gna[u]; gb[u] = gnb[u]; }
    }
}

// ---------------- FUSED: h += mh_ln(ys; GS=32)*gnw ; r = LN(h)*ffn_nw ----------------
__global__ void slstm_addnorm_ln(const float* __restrict__ ys, const float* __restrict__ gnw,
                                 const float* __restrict__ ffnw,
                                 float* __restrict__ h, float* __restrict__ r) {
    int row = blockIdx.x; int c = threadIdx.x;  // 128
    __shared__ float s1[128], s2[128];
    float v = ys[(size_t)row*128 + c];
    s1[c]=v; s2[c]=v*v; __syncthreads();
    int li = c & 31;
    for (int off=16; off>0; off>>=1){
        if (li < off){ s1[c]+=s1[c+off]; s2[c]+=s2[c+off]; }
        __syncthreads();
    }
    int base = c & ~31;
    float mu = s1[base]*(1.f/32.f);
    float var = s2[base]*(1.f/32.f) - mu*mu;
    float hn = h[(size_t)row*128 + c] + (v-mu)*rsqrtf(var+1e-5f)*gnw[c];
    h[(size_t)row*128 + c] = hn;
    __syncthreads();
    s1[c]=hn; s2[c]=hn*hn; __syncthreads();
    for (int off=64; off>0; off>>=1){
        if (c<off){ s1[c]+=s1[c+off]; s2[c]+=s2[c+off]; }
        __syncthreads();
    }
    float mu2 = s1[0]*(1.f/128.f);
    float var2 = s2[0]*(1.f/128.f) - mu2*mu2;
    r[(size_t)row*128 + c] = (hn-mu2)*rsqrtf(var2+1e-5f)*ffnw[c];
}

// ---------------- FUSED final: LN(last-token rows only) + FC ----------------
__global__ void final_ln_fc(const float* __restrict__ h, const float* __restrict__ postw,
                            const float* __restrict__ fcW, const float* __restrict__ fcb,
                            float* __restrict__ out) {
    int b = blockIdx.x; int t = threadIdx.x;  // 128
    const float* hr = h + (size_t)(b*S_ + S_-1)*128;
    float v = hr[t];
    __shared__ float s1[128], s2[128];
    s1[t]=v; s2[t]=v*v; __syncthreads();
    for (int off=64; off>0; off>>=1){
        if (t<off){ s1[t]+=s1[t+off]; s2[t]+=s2[t+off]; }
        __syncthreads();
    }
    float mu = s1[0]*(1.f/128.f);
    float var = s2[0]*(1.f/128.f) - mu*mu;
    float hp = (v-mu)*rsqrtf(var+1e-5f)*postw[t];
    __syncthreads();
    s1[t] = hp*fcW[t]; __syncthreads();
    for (int off=64; off>0; off>>=1){
        if (t<off) s1[t]+=s1[t+off];
        __syncthreads();
    }
    if (t == 0) out[b] = s1[0] + fcb[0];
}

extern "C" void kernel_launch(void* const* d_in, const int* in_sizes, int n_in,
                              void* d_out, int out_size, void* d_ws, size_t ws_size,
                              hipStream_t stream) {
    const float* x       = (const float*)d_in[0];
    const float* W_in    = (const float*)d_in[1];
    const float* b_in    = (const float*)d_in[2];
    const float* ln0_w   = (const float*)d_in[3];
    const float* m_Wup   = (const float*)d_in[4];
    const float* m_bup   = (const float*)d_in[5];
    const float* m_convk = (const float*)d_in[6];
    const float* m_convb = (const float*)d_in[7];
    const float* m_Wq    = (const float*)d_in[8];
    const float* m_bq    = (const float*)d_in[9];
    const float* m_Wk    = (const float*)d_in[10];
    const float* m_bk    = (const float*)d_in[11];
    const float* m_Wv    = (const float*)d_in[12];
    const float* m_bv    = (const float*)d_in[13];
    const float* m_Wig   = (const float*)d_in[14];
    const float* m_big   = (const float*)d_in[15];
    const float* m_Wfg   = (const float*)d_in[16];
    const float* m_bfg   = (const float*)d_in[17];
    const float* m_onw   = (const float*)d_in[18];
    const float* m_skip  = (const float*)d_in[19];
    const float* m_Wd    = (const float*)d_in[20];
    const float* m_bd    = (const float*)d_in[21];
    const float* ln1_w   = (const float*)d_in[22];
    const float* s_convk = (const float*)d_in[23];
    const float* s_convb = (const float*)d_in[24];
    const float* s_Wi    = (const float*)d_in[25];
    const float* s_Wf    = (const float*)d_in[26];
    const float* s_Wz    = (const float*)d_in[27];
    const float* s_Wo    = (const float*)d_in[28];
    const float* s_R     = (const float*)d_in[29];
    const float* s_b     = (const float*)d_in[30];
    const float* s_gnw   = (const float*)d_in[31];
    const float* ffn_nw  = (const float*)d_in[32];
    const float* f_Wu    = (const float*)d_in[33];
    const float* f_bu    = (const float*)d_in[34];
    const float* f_Wd    = (const float*)d_in[35];
    const float* f_bd    = (const float*)d_in[36];
    const float* post_w  = (const float*)d_in[37];
    const float* fc_W    = (const float*)d_in[38];
    const float* fc_b    = (const float*)d_in[39];
    float* out = (float*)d_out;

    float* W = (float*)d_ws;
    const size_t M1 = 1048576;        // 8192*128
    float* h    = W;                   // 1M
    float* r    = W + 1*M1;            // 1M
    float* up   = W + 2*M1;            // 4M
    float* xc   = W + 6*M1;            // 2M
    float* q    = W + 8*M1;            // 2M
    float* kbuf = W + 10*M1;           // 2M
    float* vbuf = W + 12*M1;           // 2M
    float* hc   = W + 14*M1;           // 2M
    float* igp  = W + 16*M1;
    float* fgp  = igp + 32768;
    float* lc   = fgp + 32768;
    float* av   = lc  + 32768;
    float* mx   = av  + 32768;
    float* hs   = q;
    float* gx   = kbuf;
    float* ys   = hc;
    float* act  = q;

    // 1. h = x @ W_in^T + b_in ; r = LN(h)*ln0_w   (fused)
    gemm_ln<<<MROWS_/64, 256, 0, stream>>>(x, W_in, b_in, nullptr, ln0_w, h, r, MROWS_, F_);
    // 2. up = r @ m_Wup^T + m_bup
    gemm_bias_big<<<dim3(512/64, MROWS_/64), 256, 0, stream>>>(r, m_Wup, m_bup, nullptr, up, MROWS_, 512, 128);
    // 3. FUSED conv+silu + q/k/v headwise + gateproj
    mlstm_qkv<<<MROWS_, 64, 0, stream>>>(up, m_convk, m_convb, m_Wq, m_bq, m_Wk, m_bk,
                                         m_Wv, m_bv, m_Wig, m_big, m_Wfg, m_bfg,
                                         xc, q, kbuf, vbuf, igp, fgp);
    // 4. decay precompute
    mlstm_scan_pre<<<B_*NH_, 1024, 0, stream>>>(igp, fgp, lc, av, mx);
    // 5. attention (tiled)
    mlstm_attn_tiled<<<B_*NH_*16, 256, 0, stream>>>(q, kbuf, vbuf, lc, av, mx, hc);
    // 6. multihead LN + skip + gate
    mlstm_out<<<MROWS_, 256, 0, stream>>>(hc, xc, up, m_onw, m_skip, hs);
    // 7. h += hs @ m_Wd^T + m_bd ; r = LN(h)*ln1_w   (fused)
    gemm_ln<<<MROWS_/64, 256, 0, stream>>>(hs, m_Wd, m_bd, h, ln1_w, h, r, MROWS_, 256);
    // 8. FUSED sLSTM conv+silu + 4-gate matvecs
    slstm_convgates<<<MROWS_, 128, 0, stream>>>(r, s_convk, s_convb, s_Wi, s_Wf, s_Wz, s_Wo, gx);
    // 9. sequential scan
    slstm_scan_wave<<<B_*NH_, 64, 0, stream>>>(gx, s_R, s_b, ys);
    // 10. FUSED h += mh_ln(ys)*gnw ; r = LN(h)*ffn_nw
    slstm_addnorm_ln<<<MROWS_, 128, 0, stream>>>(ys, s_gnw, ffn_nw, h, r);
    // 11. FUSED FFN up-GEMM + gelu(g)*u2  -> act
    gemm_ffn_act<<<dim3(3, MROWS_/64), 256, 0, stream>>>(r, f_Wu, f_bu, act, MROWS_);
    // 12. h += act @ f_Wd^T + f_bd
    gemm_bias_big<<<dim3(128/64, MROWS_/64), 256, 0, stream>>>(act, f_Wd, f_bd, h, h, MROWS_, 128, 192);
    // 13. FUSED final LN (last token only) + FC
    final_ln_fc<<<B_, 128, 0, stream>>>(h, post_w, fc_W, fc_b, out);
    (void)in_sizes; (void)n_in; (void)out_size; (void)ws_size;
}

// Round 13
// 912.490 us; speedup vs baseline: 1.0321x; 1.0321x over previous
//
#include <hip/hip_runtime.h>
#include <hip/hip_bf16.h>
#include <math.h>

#define B_ 8
#define S_ 1024
#define F_ 75
#define D_ 128
#define INNER_ 256
#define NH_ 4
#define DH_ 64
#define MROWS_ (B_*S_)   // 8192

static __device__ __forceinline__ float frcp(float x){ return __builtin_amdgcn_rcpf(x); }
static __device__ __forceinline__ float fsigm(float x){ return frcp(1.0f + __expf(-x)); }
static __device__ __forceinline__ float flogsig(float x){
    return fminf(x, 0.f) - __logf(1.0f + __expf(-fabsf(x)));
}
static __device__ __forceinline__ float ftanh(float z){
    return 1.0f - 2.0f*frcp(__expf(2.0f*z) + 1.0f);
}

// ---------------- Tiled GEMM: C = A @ W^T + bias (+ res) ----------------
__global__ __launch_bounds__(256, 2) void gemm_bias_big(
        const float* __restrict__ A, const float* __restrict__ W,
        const float* __restrict__ bias, const float* __restrict__ res,
        float* __restrict__ C, int M, int N, int K) {
    __shared__ float As[64*68];
    __shared__ float Ws[64*68];
    int tid = threadIdx.x;
    int wid = tid >> 6, lane = tid & 63;
    int wy = wid >> 1, wx = wid & 1;
    int sg = lane >> 3, tg = lane & 7;
    int m0 = blockIdx.y*64, n0 = blockIdx.x*64;
    int r = tid >> 2, c0 = (tid & 3) << 4;
    bool vec = ((K & 3) == 0);
    float acc[4][4];
    #pragma unroll
    for (int i = 0; i < 4; ++i)
        #pragma unroll
        for (int j = 0; j < 4; ++j) acc[i][j] = 0.f;

    for (int k0 = 0; k0 < K; k0 += 64) {
        __syncthreads();
        const float* Ar = A + (size_t)(m0+r)*K + k0;
        const float* Wr = W + (size_t)(n0+r)*K + k0;
        if (vec) {
            #pragma unroll
            for (int i = 0; i < 4; ++i) {
                *(float4*)(&As[r*68 + c0 + 4*i]) = *(const float4*)(Ar + c0 + 4*i);
                *(float4*)(&Ws[r*68 + c0 + 4*i]) = *(const float4*)(Wr + c0 + 4*i);
            }
        } else {
            #pragma unroll
            for (int i = 0; i < 4; ++i)
                #pragma unroll
                for (int e = 0; e < 4; ++e) {
                    int c = c0 + 4*i + e;
                    bool ok = (k0 + c) < K;
                    As[r*68 + c] = ok ? Ar[c] : 0.f;
                    Ws[r*68 + c] = ok ? Wr[c] : 0.f;
                }
        }
        __syncthreads();
        const float* arow = &As[(32*wy + sg)*68];
        const float* brow = &Ws[(32*wx + tg)*68];
        #pragma unroll 2
        for (int d = 0; d < 64; d += 4) {
            float4 b0 = *(const float4*)(brow + 0*544 + d);
            float4 b1 = *(const float4*)(brow + 1*544 + d);
            float4 b2 = *(const float4*)(brow + 2*544 + d);
            float4 b3 = *(const float4*)(brow + 3*544 + d);
            #pragma unroll
            for (int i = 0; i < 4; ++i) {
                float4 a = *(const float4*)(arow + i*544 + d);
                acc[i][0] += a.x*b0.x + a.y*b0.y + a.z*b0.z + a.w*b0.w;
                acc[i][1] += a.x*b1.x + a.y*b1.y + a.z*b1.z + a.w*b1.w;
                acc[i][2] += a.x*b2.x + a.y*b2.y + a.z*b2.z + a.w*b2.w;
                acc[i][3] += a.x*b3.x + a.y*b3.y + a.z*b3.z + a.w*b3.w;
            }
        }
    }
    #pragma unroll
    for (int i = 0; i < 4; ++i) {
        int m = m0 + 32*wy + 8*i + sg;
        #pragma unroll
        for (int j = 0; j < 4; ++j) {
            int n = n0 + 32*wx + 8*j + tg;
            float v = acc[i][j] + bias[n];
            if (res) v += res[(size_t)m*N + n];
            C[(size_t)m*N + n] = v;
        }
    }
}

// ---------------- FUSED GEMM (N=128) + LayerNorm epilogue, 32-row tiles ----------------
// 256 blocks (full GPU). 4 waves in 2x2: wave(wy,wx) owns rows 16wy..+15,
// cols 64wx..+63; lane acc[2][8] (rows 16wy+8i+sg, cols 64wx+8j+tg).
// LN row-sum: tg-butterfly (xor 1,2,4) + 2-entry LDS cross-wx combine.
__global__ __launch_bounds__(256, 2) void gemm_ln(
        const float* __restrict__ A, const float* __restrict__ W,
        const float* __restrict__ bias, const float* __restrict__ res,
        const float* __restrict__ lnw, float* __restrict__ H,
        float* __restrict__ Rout, int M, int K) {
    __shared__ float As[32*68];
    __shared__ float Ws[128*68];
    __shared__ float Lsum[2][32], Lssq[2][32];
    int tid = threadIdx.x;
    int wid = tid >> 6, lane = tid & 63;
    int wy = wid >> 1, wx = wid & 1;
    int sg = lane >> 3, tg = lane & 7;
    int m0 = blockIdx.x*32;
    int ra = tid >> 3, ca0 = (tid & 7) << 3;   // A staging: 32 rows x 64 (8 f/thread)
    int rw = tid >> 1, cw0 = (tid & 1) << 5;   // W staging: 128 rows x 64 (32 f/thread)
    bool vec = ((K & 3) == 0);
    float acc[2][8];
    #pragma unroll
    for (int i = 0; i < 2; ++i)
        #pragma unroll
        for (int j = 0; j < 8; ++j) acc[i][j] = 0.f;

    for (int k0 = 0; k0 < K; k0 += 64) {
        __syncthreads();
        const float* Ar = A + (size_t)(m0+ra)*K + k0;
        const float* Wr = W + (size_t)rw*K + k0;
        if (vec) {
            *(float4*)(&As[ra*68 + ca0])     = *(const float4*)(Ar + ca0);
            *(float4*)(&As[ra*68 + ca0 + 4]) = *(const float4*)(Ar + ca0 + 4);
            #pragma unroll
            for (int i = 0; i < 8; ++i)
                *(float4*)(&Ws[rw*68 + cw0 + 4*i]) = *(const float4*)(Wr + cw0 + 4*i);
        } else {
            #pragma unroll
            for (int e = 0; e < 8; ++e) {
                int c = ca0 + e;
                As[ra*68 + c] = ((k0 + c) < K) ? Ar[c] : 0.f;
            }
            #pragma unroll
            for (int i = 0; i < 8; ++i)
                #pragma unroll
                for (int e = 0; e < 4; ++e) {
                    int c = cw0 + 4*i + e;
                    Ws[rw*68 + c] = ((k0 + c) < K) ? Wr[c] : 0.f;
                }
        }
        __syncthreads();
        const float* arow0 = &As[(16*wy + sg)*68];
        const float* arow1 = arow0 + 8*68;
        const float* brow  = &Ws[(64*wx + tg)*68];
        #pragma unroll 1
        for (int d = 0; d < 64; d += 4) {
            float4 a0 = *(const float4*)(arow0 + d);
            float4 a1 = *(const float4*)(arow1 + d);
            #pragma unroll
            for (int j = 0; j < 8; ++j) {
                float4 b = *(const float4*)(brow + j*544 + d);
                acc[0][j] += a0.x*b.x + a0.y*b.y + a0.z*b.z + a0.w*b.w;
                acc[1][j] += a1.x*b.x + a1.y*b.y + a1.z*b.z + a1.w*b.w;
            }
        }
    }
    // epilogue: finish values + per-row sum/sumsq
    float ps[2], pss[2];
    #pragma unroll
    for (int i = 0; i < 2; ++i) {
        int m = m0 + 16*wy + 8*i + sg;
        float s = 0.f, ss = 0.f;
        #pragma unroll
        for (int j = 0; j < 8; ++j) {
            int n = 64*wx + 8*j + tg;
            float vv = acc[i][j] + bias[n];
            if (res) vv += res[(size_t)m*128 + n];
            acc[i][j] = vv;
            s += vv; ss += vv*vv;
        }
        ps[i] = s; pss[i] = ss;
    }
    #pragma unroll
    for (int bm = 1; bm <= 4; bm <<= 1)
        #pragma unroll
        for (int i = 0; i < 2; ++i) {
            ps[i]  += __shfl_xor(ps[i],  bm, 64);
            pss[i] += __shfl_xor(pss[i], bm, 64);
        }
    if (tg == 0) {
        #pragma unroll
        for (int i = 0; i < 2; ++i) {
            int rloc = 16*wy + 8*i + sg;
            Lsum[wx][rloc] = ps[i];
            Lssq[wx][rloc] = pss[i];
        }
    }
    __syncthreads();
    #pragma unroll
    for (int i = 0; i < 2; ++i) {
        int rloc = 16*wy + 8*i + sg;
        int m = m0 + rloc;
        float s  = Lsum[0][rloc] + Lsum[1][rloc];
        float ss = Lssq[0][rloc] + Lssq[1][rloc];
        float mu = s*(1.f/128.f);
        float var = ss*(1.f/128.f) - mu*mu;
        float inv = rsqrtf(var + 1e-5f);
        #pragma unroll
        for (int j = 0; j < 8; ++j) {
            int n = 64*wx + 8*j + tg;
            float vv = acc[i][j];
            H[(size_t)m*128 + n]    = vv;
            Rout[(size_t)m*128 + n] = (vv-mu)*inv*lnw[n];
        }
    }
}

// ---------------- FUSED FFN up-GEMM + gelu(g)*u2 epilogue ----------------
__global__ __launch_bounds__(256, 2) void gemm_ffn_act(
        const float* __restrict__ A, const float* __restrict__ Wu,
        const float* __restrict__ bu, float* __restrict__ act, int M) {
    __shared__ float As[64*68];
    __shared__ float Wg[64*68];
    __shared__ float Wu2[64*68];
    int tid = threadIdx.x;
    int wid = tid >> 6, lane = tid & 63;
    int wy = wid >> 1, wx = wid & 1;
    int sg = lane >> 3, tg = lane & 7;
    int m0 = blockIdx.y*64, nb = blockIdx.x*64;
    int r = tid >> 2, c0 = (tid & 3) << 4;
    float ag[4][4], au[4][4];
    #pragma unroll
    for (int i = 0; i < 4; ++i)
        #pragma unroll
        for (int j = 0; j < 4; ++j) { ag[i][j] = 0.f; au[i][j] = 0.f; }

    for (int k0 = 0; k0 < 128; k0 += 64) {
        __syncthreads();
        const float* Ar = A + (size_t)(m0+r)*128 + k0;
        const float* Wgr = Wu + (size_t)(nb+r)*128 + k0;
        const float* Wur = Wu + (size_t)(192+nb+r)*128 + k0;
        #pragma unroll
        for (int i = 0; i < 4; ++i) {
            *(float4*)(&As[r*68 + c0 + 4*i])  = *(const float4*)(Ar + c0 + 4*i);
            *(float4*)(&Wg[r*68 + c0 + 4*i])  = *(const float4*)(Wgr + c0 + 4*i);
            *(float4*)(&Wu2[r*68 + c0 + 4*i]) = *(const float4*)(Wur + c0 + 4*i);
        }
        __syncthreads();
        const float* arow = &As[(32*wy + sg)*68];
        const float* grow = &Wg[(32*wx + tg)*68];
        const float* urow = &Wu2[(32*wx + tg)*68];
        #pragma unroll 2
        for (int d = 0; d < 64; d += 4) {
            float4 g0 = *(const float4*)(grow + 0*544 + d);
            float4 g1 = *(const float4*)(grow + 1*544 + d);
            float4 g2 = *(const float4*)(grow + 2*544 + d);
            float4 g3 = *(const float4*)(grow + 3*544 + d);
            float4 u0 = *(const float4*)(urow + 0*544 + d);
            float4 u1 = *(const float4*)(urow + 1*544 + d);
            float4 u2 = *(const float4*)(urow + 2*544 + d);
            float4 u3 = *(const float4*)(urow + 3*544 + d);
            #pragma unroll
            for (int i = 0; i < 4; ++i) {
                float4 a = *(const float4*)(arow + i*544 + d);
                ag[i][0] += a.x*g0.x + a.y*g0.y + a.z*g0.z + a.w*g0.w;
                ag[i][1] += a.x*g1.x + a.y*g1.y + a.z*g1.z + a.w*g1.w;
                ag[i][2] += a.x*g2.x + a.y*g2.y + a.z*g2.z + a.w*g2.w;
                ag[i][3] += a.x*g3.x + a.y*g3.y + a.z*g3.z + a.w*g3.w;
                au[i][0] += a.x*u0.x + a.y*u0.y + a.z*u0.z + a.w*u0.w;
                au[i][1] += a.x*u1.x + a.y*u1.y + a.z*u1.z + a.w*u1.w;
                au[i][2] += a.x*u2.x + a.y*u2.y + a.z*u2.z + a.w*u2.w;
                au[i][3] += a.x*u3.x + a.y*u3.y + a.z*u3.z + a.w*u3.w;
            }
        }
    }
    #pragma unroll
    for (int i = 0; i < 4; ++i) {
        int m = m0 + 32*wy + 8*i + sg;
        #pragma unroll
        for (int j = 0; j < 4; ++j) {
            int n = nb + 32*wx + 8*j + tg;
            float g  = ag[i][j] + bu[n];
            float u2 = au[i][j] + bu[192+n];
            float ge = 0.5f*g*(1.0f + erff(g*0.70710678118f));
            act[(size_t)m*192 + n] = ge*u2;
        }
    }
}

// ---------------- FUSED mLSTM front-end: conv+silu, q/k/v headwise, gateproj ----------------
__global__ __launch_bounds__(64) void mlstm_qkv(
        const float* __restrict__ up, const float* __restrict__ convk,
        const float* __restrict__ convb,
        const float* __restrict__ Wq, const float* __restrict__ bq,
        const float* __restrict__ Wk, const float* __restrict__ bk,
        const float* __restrict__ Wv, const float* __restrict__ bv,
        const float* __restrict__ Wig, const float* __restrict__ big,
        const float* __restrict__ Wfg, const float* __restrict__ bfg,
        float* __restrict__ xc, float* __restrict__ q, float* __restrict__ k,
        float* __restrict__ v, float* __restrict__ igp, float* __restrict__ fgp) {
    int row = blockIdx.x;
    int b = row >> 10, s = row & 1023;
    int l = threadIdx.x;
    int c0 = l*4;
    float4 xm[4];
    #pragma unroll
    for (int i = 0; i < 4; ++i) {
        int sp = s - 3 + i;
        if (sp >= 0) xm[i] = *(const float4*)(up + (size_t)(row-3+i)*512 + c0);
        else         xm[i] = make_float4(0.f,0.f,0.f,0.f);
    }
    float xcv[4];
    #pragma unroll
    for (int j = 0; j < 4; ++j) {
        int c = c0 + j;
        float acc = convb[c];
        #pragma unroll
        for (int i = 0; i < 4; ++i)
            acc += ((const float*)&xm[i])[j] * convk[c*4+i];
        xcv[j] = acc * fsigm(acc);
    }
    *(float4*)(xc + (size_t)row*256 + c0) = make_float4(xcv[0],xcv[1],xcv[2],xcv[3]);
    float qv[4], kv[4], vv[4];
    #pragma unroll
    for (int o = 0; o < 4; ++o) {
        const float* wq = Wq + ((size_t)l*4 + o)*4;
        const float* wk = Wk + ((size_t)l*4 + o)*4;
        const float* wv = Wv + ((size_t)l*4 + o)*4;
        float aq = bq[c0+o], ak = bk[c0+o], avv = bv[c0+o];
        #pragma unroll
        for (int i = 0; i < 4; ++i) {
            aq  += xcv[i]*wq[i];
            ak  += xcv[i]*wk[i];
            avv += ((const float*)&xm[3])[i]*wv[i];
        }
        qv[o]=aq; kv[o]=ak; vv[o]=avv;
    }
    *(float4*)(q + (size_t)row*256 + c0) = make_float4(qv[0],qv[1],qv[2],qv[3]);
    *(float4*)(k + (size_t)row*256 + c0) = make_float4(kv[0],kv[1],kv[2],kv[3]);
    *(float4*)(v + (size_t)row*256 + c0) = make_float4(vv[0],vv[1],vv[2],vv[3]);
    float dots[8];
    #pragma unroll
    for (int g = 0; g < 4; ++g) {
        float di = 0.f, df = 0.f;
        #pragma unroll
        for (int j = 0; j < 4; ++j) {
            di += qv[j]*Wig[g*768 + c0 + j] + kv[j]*Wig[g*768 + 256 + c0 + j]
                + vv[j]*Wig[g*768 + 512 + c0 + j];
            df += qv[j]*Wfg[g*768 + c0 + j] + kv[j]*Wfg[g*768 + 256 + c0 + j]
                + vv[j]*Wfg[g*768 + 512 + c0 + j];
        }
        dots[g] = di; dots[4+g] = df;
    }
    #pragma unroll
    for (int off = 32; off > 0; off >>= 1)
        #pragma unroll
        for (int g = 0; g < 8; ++g) dots[g] += __shfl_down(dots[g], off, 64);
    if (l == 0) {
        #pragma unroll
        for (int g = 0; g < 4; ++g) {
            igp[((size_t)b*NH_+g)*S_ + s] = dots[g]   + big[g];
            fgp[((size_t)b*NH_+g)*S_ + s] = dots[4+g] + bfg[g];
        }
    }
}

// ---------------- FUSED sLSTM front-end: conv+silu + all-4-gate matvecs ----------------
__global__ __launch_bounds__(128) void slstm_convgates(
        const float* __restrict__ r, const float* __restrict__ convk,
        const float* __restrict__ convb, const float* __restrict__ Wi,
        const float* __restrict__ Wf, const float* __restrict__ Wz,
        const float* __restrict__ Wo, float* __restrict__ GX) {
    int row = blockIdx.x; int s = row & 1023;
    int c = threadIdx.x;
    __shared__ float rcL[128], rL[128];
    float rv = r[(size_t)row*128 + c];
    float acc = convb[c];
    #pragma unroll
    for (int i = 0; i < 4; ++i) {
        int sp = s - 3 + i;
        if (sp >= 0) acc += r[(size_t)(row-3+i)*128 + c]*convk[c*4+i];
    }
    float rcv = acc * fsigm(acc);
    rcL[c] = rcv; rL[c] = rv;
    __syncthreads();
    int h = c >> 5, o = c & 31;
    size_t wb = ((size_t)h*32 + o)*32;
    const float* rc_ = rcL + h*32;
    const float* rr_ = rL + h*32;
    float di=0.f, df=0.f, dz=0.f, doo=0.f;
    #pragma unroll
    for (int i = 0; i < 32; ++i) {
        float a = rc_[i], cc = rr_[i];
        di  += a*Wi[wb+i];
        df  += a*Wf[wb+i];
        dz  += cc*Wz[wb+i];
        doo += cc*Wo[wb+i];
    }
    float* g = GX + (size_t)row*512 + h*128 + o;
    g[0]  = di;
    g[32] = df;
    g[64] = dz;
    g[96] = doo;
}

// ---------------- mLSTM decay precompute ----------------
__global__ void mlstm_scan_pre(const float* __restrict__ igp, const float* __restrict__ fgp,
                               float* __restrict__ lc, float* __restrict__ av,
                               float* __restrict__ mx) {
    int bh = blockIdx.x; int t = threadIdx.x;  // 1024 threads
    __shared__ float buf[2][1024];
    float ls = flogsig(fgp[(size_t)bh*S_ + t]);
    int cur = 0;
    buf[0][t] = ls; __syncthreads();
    for (int off=1; off<1024; off<<=1) {
        float x2 = buf[cur][t];
        if (t >= off) x2 += buf[cur][t-off];
        buf[cur^1][t] = x2; cur ^= 1; __syncthreads();
    }
    float lcv = buf[cur][t];
    lc[(size_t)bh*S_+t] = lcv;
    float a = igp[(size_t)bh*S_+t] - lcv;
    av[(size_t)bh*S_+t] = a;
    __syncthreads();
    cur = 0; buf[0][t] = a; __syncthreads();
    for (int off=1; off<1024; off<<=1) {
        float x2 = buf[cur][t];
        if (t >= off) x2 = fmaxf(x2, buf[cur][t-off]);
        buf[cur^1][t] = x2; cur ^= 1; __syncthreads();
    }
    mx[(size_t)bh*S_+t] = buf[cur][t];
}

// ---------------- mLSTM attention: tiled flash-style ----------------
__global__ __launch_bounds__(256, 2) void mlstm_attn_tiled(
        const float* __restrict__ q, const float* __restrict__ k,
        const float* __restrict__ v, const float* __restrict__ lc,
        const float* __restrict__ av, const float* __restrict__ mx,
        float* __restrict__ hc) {
    int bid = blockIdx.x;
    int stile = 15 - (bid & 15);
    int bh = bid >> 4;
    int hh = bh & 3, b = bh >> 2;
    int s0 = stile << 6;
    int tid = threadIdx.x;
    int wid = tid >> 6, lane = tid & 63;
    int wy = wid >> 1, wx = wid & 1;
    int sg = lane >> 3, tg = lane & 7;

    __shared__ float qs[64*68];
    __shared__ float kst[64*68];
    __shared__ float vtT[64*68];
    __shared__ float avt[64], maxsL[64], normL[64], rsumL[128];

    const size_t bhS = (size_t)bh * S_;
    {
        int r = tid >> 2, c0 = (tid & 3) << 4;
        const float* qg = q + ((size_t)(b*S_) + s0 + r)*INNER_ + hh*64;
        #pragma unroll
        for (int i = 0; i < 4; ++i) {
            float4 t4 = *(const float4*)(qg + c0 + 4*i);
            float4 w4; w4.x=t4.x*0.125f; w4.y=t4.y*0.125f; w4.z=t4.z*0.125f; w4.w=t4.w*0.125f;
            *(float4*)(&qs[r*68 + c0 + 4*i]) = w4;
        }
        if (tid < 64) maxsL[tid] = lc[bhS + s0 + tid] + mx[bhS + s0 + tid];
    }
    float msv[4];
    #pragma unroll
    for (int i = 0; i < 4; ++i)
        msv[i] = mx[bhS + s0 + 32*wy + 8*i + sg];

    float O[4][4];
    float rsAcc[4];
    #pragma unroll
    for (int i = 0; i < 4; ++i) {
        rsAcc[i] = 0.f;
        #pragma unroll
        for (int j = 0; j < 4; ++j) O[i][j] = 0.f;
    }

    for (int t0 = 0; t0 <= s0; t0 += 64) {
        __syncthreads();
        {
            int r = tid >> 2, c0 = (tid & 3) << 4;
            const float* kg = k + ((size_t)(b*S_) + t0 + r)*INNER_ + hh*64;
            const float* vg = v + ((size_t)(b*S_) + t0 + r)*INNER_ + hh*64;
            #pragma unroll
            for (int i = 0; i < 4; ++i) {
                *(float4*)(&kst[r*68 + c0 + 4*i]) = *(const float4*)(kg + c0 + 4*i);
                float4 v4 = *(const float4*)(vg + c0 + 4*i);
                int dc = c0 + 4*i;
                vtT[(dc+0)*68 + r] = v4.x;
                vtT[(dc+1)*68 + r] = v4.y;
                vtT[(dc+2)*68 + r] = v4.z;
                vtT[(dc+3)*68 + r] = v4.w;
            }
            if (tid < 64) avt[tid] = av[bhS + t0 + tid];
        }
        __syncthreads();
        float dot[4][4];
        #pragma unroll
        for (int i = 0; i < 4; ++i)
            #pragma unroll
            for (int j = 0; j < 4; ++j) dot[i][j] = 0.f;
        {
            const float* qrow = &qs[(32*wy + sg)*68];
            const float* krow = &kst[(32*wx + tg)*68];
            #pragma unroll 2
            for (int d = 0; d < 64; d += 4) {
                float4 b0 = *(const float4*)(krow + 0*544 + d);
                float4 b1 = *(const float4*)(krow + 1*544 + d);
                float4 b2 = *(const float4*)(krow + 2*544 + d);
                float4 b3 = *(const float4*)(krow + 3*544 + d);
                #pragma unroll
                for (int i = 0; i < 4; ++i) {
                    float4 a = *(const float4*)(qrow + i*544 + d);
                    dot[i][0] += a.x*b0.x + a.y*b0.y + a.z*b0.z + a.w*b0.w;
                    dot[i][1] += a.x*b1.x + a.y*b1.y + a.z*b1.z + a.w*b1.w;
                    dot[i][2] += a.x*b2.x + a.y*b2.y + a.z*b2.z + a.w*b2.w;
                    dot[i][3] += a.x*b3.x + a.y*b3.y + a.z*b3.z + a.w*b3.w;
                }
            }
        }
        __syncthreads();
        #pragma unroll
        for (int i = 0; i < 4; ++i) {
            int s_loc = 32*wy + 8*i + sg;
            float rp = 0.f;
            #pragma unroll
            for (int j = 0; j < 4; ++j) {
                int t_loc = 32*wx + 8*j + tg;
                bool ok = (t0 + t_loc) <= (s0 + s_loc);
                float p = ok ? dot[i][j]*__expf(avt[t_loc] - msv[i]) : 0.f;
                kst[s_loc*68 + t_loc] = p;
                rp += p;
            }
            rp += __shfl_xor(rp, 1);
            rp += __shfl_xor(rp, 2);
            rp += __shfl_xor(rp, 4);
            rsAcc[i] += rp;
        }
        __syncthreads();
        {
            const float* prow = &kst[(32*wy + sg)*68];
            const float* vrow = &vtT[(32*wx + tg)*68];
            #pragma unroll 2
            for (int tt = 0; tt < 64; tt += 4) {
                float4 b0 = *(const float4*)(vrow + 0*544 + tt);
                float4 b1 = *(const float4*)(vrow + 1*544 + tt);
                float4 b2 = *(const float4*)(vrow + 2*544 + tt);
                float4 b3 = *(const float4*)(vrow + 3*544 + tt);
                #pragma unroll
                for (int i = 0; i < 4; ++i) {
                    float4 a = *(const float4*)(prow + i*544 + tt);
                    O[i][0] += a.x*b0.x + a.y*b0.y + a.z*b0.z + a.w*b0.w;
                    O[i][1] += a.x*b1.x + a.y*b1.y + a.z*b1.z + a.w*b1.w;
                    O[i][2] += a.x*b2.x + a.y*b2.y + a.z*b2.z + a.w*b2.w;
                    O[i][3] += a.x*b3.x + a.y*b3.y + a.z*b3.z + a.w*b3.w;
                }
            }
        }
    }
    if (tg == 0) {
        #pragma unroll
        for (int i = 0; i < 4; ++i)
            rsumL[wx*64 + 32*wy + 8*i + sg] = rsAcc[i];
    }
    __syncthreads();
    if (tid < 64) {
        float tot = rsumL[tid] + rsumL[64 + tid];
        normL[tid] = fmaxf(fabsf(tot), __expf(-maxsL[tid])) + 1e-6f;
    }
    __syncthreads();
    #pragma unroll
    for (int i = 0; i < 4; ++i) {
        int s_loc = 32*wy + 8*i + sg;
        float inv = 1.0f / normL[s_loc];
        #pragma unroll
        for (int j = 0; j < 4; ++j) {
            int d_loc = 32*wx + 8*j + tg;
            hc[((size_t)(b*S_) + s0 + s_loc)*INNER_ + hh*64 + d_loc] = O[i][j] * inv;
        }
    }
}

// ---------------- mLSTM output: multihead LN (GS=64) + skip + gate ----------------
__global__ void mlstm_out(const float* __restrict__ hc, const float* __restrict__ xc,
                          const float* __restrict__ up, const float* __restrict__ onw,
                          const float* __restrict__ skip, float* __restrict__ hs) {
    int row = blockIdx.x; int c = threadIdx.x;  // 256 threads
    float v = hc[(size_t)row*INNER_ + c];
    __shared__ float s1[256], s2[256];
    s1[c]=v; s2[c]=v*v; __syncthreads();
    int li = c & 63;
    for (int off=32; off>0; off>>=1){
        if (li < off){ s1[c]+=s1[c+off]; s2[c]+=s2[c+off]; }
        __syncthreads();
    }
    int base = c & ~63;
    float mu = s1[base]*(1.f/64.f);
    float var = s2[base]*(1.f/64.f) - mu*mu;
    float ht = (v-mu)*rsqrtf(var+1e-5f)*onw[c];
    float z = up[(size_t)row*512 + 256 + c];
    hs[(size_t)row*INNER_ + c] = (ht + skip[c]*xc[(size_t)row*INNER_+c]) * (z*fsigm(z));
}

// ---------------- sLSTM scan: pair-lane layout, DPP gate exchange ----------------
__global__ __launch_bounds__(64, 1) void slstm_scan_wave(
        const float* __restrict__ gx, const float* __restrict__ R,
        const float* __restrict__ bb, float* __restrict__ ys) {
    int blk = blockIdx.x; int hh = blk & 3; int b = blk >> 2;
    int l = threadIdx.x;  // 0..63
    int e = l >> 1, p = l & 1;
    int o0 = p*32 + e, o1 = (p+2)*32 + e;
    float Rc0[32], Rc1[32];
    #pragma unroll
    for (int d = 0; d < 32; ++d) {
        Rc0[d] = R[(size_t)(hh*32 + d)*128 + o0];
        Rc1[d] = R[(size_t)(hh*32 + d)*128 + o1];
        asm volatile("" : "+v"(Rc0[d]));
        asm volatile("" : "+v"(Rc1[d]));
    }
    float bj0 = bb[hh*128 + o0], bj1 = bb[hh*128 + o1];
    float cst = 0.f, nst = 0.f, mst = 0.f, y = 0.f;
    const float* gbase = gx + (size_t)(b*S_)*512 + hh*128;
    float* ybase = ys + (size_t)(b*S_)*128 + hh*32 + e;
    float ga[4], gb[4];
    #pragma unroll
    for (int u = 0; u < 4; ++u) {
        ga[u] = gbase[(size_t)u*512 + o0];
        gb[u] = gbase[(size_t)u*512 + o1];
    }
    for (int t = 0; t < S_; t += 4) {
        float gna[4], gnb[4];
        #pragma unroll
        for (int u = 0; u < 4; ++u) {
            int tn = t + 4 + u;
            size_t off = (size_t)(tn < S_ ? tn : 0) * 512;
            gna[u] = gbase[off + o0];
            gnb[u] = gbase[off + o1];
        }
        #pragma unroll
        for (int u = 0; u < 4; ++u) {
            float a0=0.f, a1=0.f, a2=0.f, a3=0.f;
            float c0=0.f, c1=0.f, c2=0.f, c3=0.f;
            #pragma unroll
            for (int d = 0; d < 32; d += 4) {
                float y0 = __int_as_float(__builtin_amdgcn_readlane(__float_as_int(y), 2*d));
                float y1 = __int_as_float(__builtin_amdgcn_readlane(__float_as_int(y), 2*d+2));
                float y2 = __int_as_float(__builtin_amdgcn_readlane(__float_as_int(y), 2*d+4));
                float y3 = __int_as_float(__builtin_amdgcn_readlane(__float_as_int(y), 2*d+6));
                a0 += y0*Rc0[d];   c0 += y0*Rc1[d];
                a1 += y1*Rc0[d+1]; c1 += y1*Rc1[d+1];
                a2 += y2*Rc0[d+2]; c2 += y2*Rc1[d+2];
                a3 += y3*Rc0[d+3]; c3 += y3*Rc1[d+3];
            }
            float r0 = ga[u] + bj0 + ((a0+a1)+(a2+a3));
            float r1 = gb[u] + bj1 + ((c0+c1)+(c2+c3));
            float fo0 = __int_as_float(__builtin_amdgcn_mov_dpp(__float_as_int(r0), 0xB1, 0xF, 0xF, true));
            float fo1 = __int_as_float(__builtin_amdgcn_mov_dpp(__float_as_int(r1), 0xB1, 0xF, 0xF, true));
            float iraw = p ? fo0 : r0;
            float fraw = p ? r0 : fo0;
            float zraw = p ? fo1 : r1;
            float oraw = p ? r1 : fo1;
            int t_abs = t + u;
            float lfm = mst + flogsig(fraw);
            float mnew = (t_abs == 0) ? iraw : fmaxf(iraw, lfm);
            float igv = __expf(iraw - mnew), fgv = __expf(lfm - mnew);
            cst = fgv*cst + igv*ftanh(zraw);
            nst = fgv*nst + igv;
            mst = mnew;
            y = cst * frcp(nst * (1.0f + __expf(-oraw)));
            if (p == 0) ybase[(size_t)t_abs*128] = y;
        }
        #pragma unroll
        for (int u = 0; u < 4; ++u) { ga[u] = gna[u]; gb[u] = gnb[u]; }
    }
}

// ---------------- FUSED: h += mh_ln(ys; GS=32)*gnw ; r = LN(h)*ffn_nw ----------------
__global__ void slstm_addnorm_ln(const float* __restrict__ ys, const float* __restrict__ gnw,
                                 const float* __restrict__ ffnw,
                                 float* __restrict__ h, float* __restrict__ r) {
    int row = blockIdx.x; int c = threadIdx.x;  // 128
    __shared__ float s1[128], s2[128];
    float v = ys[(size_t)row*128 + c];
    s1[c]=v; s2[c]=v*v; __syncthreads();
    int li = c & 31;
    for (int off=16; off>0; off>>=1){
        if (li < off){ s1[c]+=s1[c+off]; s2[c]+=s2[c+off]; }
        __syncthreads();
    }
    int base = c & ~31;
    float mu = s1[base]*(1.f/32.f);
    float var = s2[base]*(1.f/32.f) - mu*mu;
    float hn = h[(size_t)row*128 + c] + (v-mu)*rsqrtf(var+1e-5f)*gnw[c];
    h[(size_t)row*128 + c] = hn;
    __syncthreads();
    s1[c]=hn; s2[c]=hn*hn; __syncthreads();
    for (int off=64; off>0; off>>=1){
        if (c<off){ s1[c]+=s1[c+off]; s2[c]+=s2[c+off]; }
        __syncthreads();
    }
    float mu2 = s1[0]*(1.f/128.f);
    float var2 = s2[0]*(1.f/128.f) - mu2*mu2;
    r[(size_t)row*128 + c] = (hn-mu2)*rsqrtf(var2+1e-5f)*ffnw[c];
}

// ---------------- FUSED final: LN(last-token rows only) + FC ----------------
__global__ void final_ln_fc(const float* __restrict__ h, const float* __restrict__ postw,
                            const float* __restrict__ fcW, const float* __restrict__ fcb,
                            float* __restrict__ out) {
    int b = blockIdx.x; int t = threadIdx.x;  // 128
    const float* hr = h + (size_t)(b*S_ + S_-1)*128;
    float v = hr[t];
    __shared__ float s1[128], s2[128];
    s1[t]=v; s2[t]=v*v; __syncthreads();
    for (int off=64; off>0; off>>=1){
        if (t<off){ s1[t]+=s1[t+off]; s2[t]+=s2[t+off]; }
        __syncthreads();
    }
    float mu = s1[0]*(1.f/128.f);
    float var = s2[0]*(1.f/128.f) - mu*mu;
    float hp = (v-mu)*rsqrtf(var+1e-5f)*postw[t];
    __syncthreads();
    s1[t] = hp*fcW[t]; __syncthreads();
    for (int off=64; off>0; off>>=1){
        if (t<off) s1[t]+=s1[t+off];
        __syncthreads();
    }
    if (t == 0) out[b] = s1[0] + fcb[0];
}

extern "C" void kernel_launch(void* const* d_in, const int* in_sizes, int n_in,
                              void* d_out, int out_size, void* d_ws, size_t ws_size,
                              hipStream_t stream) {
    const float* x       = (const float*)d_in[0];
    const float* W_in    = (const float*)d_in[1];
    const float* b_in    = (const float*)d_in[2];
    const float* ln0_w   = (const float*)d_in[3];
    const float* m_Wup   = (const float*)d_in[4];
    const float* m_bup   = (const float*)d_in[5];
    const float* m_convk = (const float*)d_in[6];
    const float* m_convb = (const float*)d_in[7];
    const float* m_Wq    = (const float*)d_in[8];
    const float* m_bq    = (const float*)d_in[9];
    const float* m_Wk    = (const float*)d_in[10];
    const float* m_bk    = (const float*)d_in[11];
    const float* m_Wv    = (const float*)d_in[12];
    const float* m_bv    = (const float*)d_in[13];
    const float* m_Wig   = (const float*)d_in[14];
    const float* m_big   = (const float*)d_in[15];
    const float* m_Wfg   = (const float*)d_in[16];
    const float* m_bfg   = (const float*)d_in[17];
    const float* m_onw   = (const float*)d_in[18];
    const float* m_skip  = (const float*)d_in[19];
    const float* m_Wd    = (const float*)d_in[20];
    const float* m_bd    = (const float*)d_in[21];
    const float* ln1_w   = (const float*)d_in[22];
    const float* s_convk = (const float*)d_in[23];
    const float* s_convb = (const float*)d_in[24];
    const float* s_Wi    = (const float*)d_in[25];
    const float* s_Wf    = (const float*)d_in[26];
    const float* s_Wz    = (const float*)d_in[27];
    const float* s_Wo    = (const float*)d_in[28];
    const float* s_R     = (const float*)d_in[29];
    const float* s_b     = (const float*)d_in[30];
    const float* s_gnw   = (const float*)d_in[31];
    const float* ffn_nw  = (const float*)d_in[32];
    const float* f_Wu    = (const float*)d_in[33];
    const float* f_bu    = (const float*)d_in[34];
    const float* f_Wd    = (const float*)d_in[35];
    const float* f_bd    = (const float*)d_in[36];
    const float* post_w  = (const float*)d_in[37];
    const float* fc_W    = (const float*)d_in[38];
    const float* fc_b    = (const float*)d_in[39];
    float* out = (float*)d_out;

    float* W = (float*)d_ws;
    const size_t M1 = 1048576;        // 8192*128
    float* h    = W;                   // 1M
    float* r    = W + 1*M1;            // 1M
    float* up   = W + 2*M1;            // 4M
    float* xc   = W + 6*M1;            // 2M
    float* q    = W + 8*M1;            // 2M
    float* kbuf = W + 10*M1;           // 2M
    float* vbuf = W + 12*M1;           // 2M
    float* hc   = W + 14*M1;           // 2M
    float* igp  = W + 16*M1;
    float* fgp  = igp + 32768;
    float* lc   = fgp + 32768;
    float* av   = lc  + 32768;
    float* mx   = av  + 32768;
    float* hs   = q;
    float* gx   = kbuf;
    float* ys   = hc;
    float* act  = q;

    // 1. h = x @ W_in^T + b_in ; r = LN(h)*ln0_w   (fused, 32-row tiles, 256 blocks)
    gemm_ln<<<MROWS_/32, 256, 0, stream>>>(x, W_in, b_in, nullptr, ln0_w, h, r, MROWS_, F_);
    // 2. up = r @ m_Wup^T + m_bup
    gemm_bias_big<<<dim3(512/64, MROWS_/64), 256, 0, stream>>>(r, m_Wup, m_bup, nullptr, up, MROWS_, 512, 128);
    // 3. FUSED conv+silu + q/k/v headwise + gateproj
    mlstm_qkv<<<MROWS_, 64, 0, stream>>>(up, m_convk, m_convb, m_Wq, m_bq, m_Wk, m_bk,
                                         m_Wv, m_bv, m_Wig, m_big, m_Wfg, m_bfg,
                                         xc, q, kbuf, vbuf, igp, fgp);
    // 4. decay precompute
    mlstm_scan_pre<<<B_*NH_, 1024, 0, stream>>>(igp, fgp, lc, av, mx);
    // 5. attention (tiled)
    mlstm_attn_tiled<<<B_*NH_*16, 256, 0, stream>>>(q, kbuf, vbuf, lc, av, mx, hc);
    // 6. multihead LN + skip + gate
    mlstm_out<<<MROWS_, 256, 0, stream>>>(hc, xc, up, m_onw, m_skip, hs);
    // 7. h += hs @ m_Wd^T + m_bd ; r = LN(h)*ln1_w   (fused)
    gemm_ln<<<MROWS_/32, 256, 0, stream>>>(hs, m_Wd, m_bd, h, ln1_w, h, r, MROWS_, 256);
    // 8. FUSED sLSTM conv+silu + 4-gate matvecs
    slstm_convgates<<<MROWS_, 128, 0, stream>>>(r, s_convk, s_convb, s_Wi, s_Wf, s_Wz, s_Wo, gx);
    // 9. sequential scan
    slstm_scan_wave<<<B_*NH_, 64, 0, stream>>>(gx, s_R, s_b, ys);
    // 10. FUSED h += mh_ln(ys)*gnw ; r = LN(h)*ffn_nw
    slstm_addnorm_ln<<<MROWS_, 128, 0, stream>>>(ys, s_gnw, ffn_nw, h, r);
    // 11. FUSED FFN up-GEMM + gelu(g)*u2  -> act
    gemm_ffn_act<<<dim3(3, MROWS_/64), 256, 0, stream>>>(r, f_Wu, f_bu, act, MROWS_);
    // 12. h += act @ f_Wd^T + f_bd
    gemm_bias_big<<<dim3(128/64, MROWS_/64), 256, 0, stream>>>(act, f_Wd, f_bd, h, h, MROWS_, 128, 192);
    // 13. FUSED final LN (last token only) + FC
    final_ln_fc<<<B_, 128, 0, stream>>>(h, post_w, fc_W, fc_b, out);
    (void)in_sizes; (void)n_in; (void)out_size; (void)ws_size;
}

// Round 14
// 908.853 us; speedup vs baseline: 1.0362x; 1.0040x over previous
//
#include <hip/hip_runtime.h>
#include <hip/hip_bf16.h>
#include <math.h>

#define B_ 8
#define S_ 1024
#define F_ 75
#define D_ 128
#define INNER_ 256
#define NH_ 4
#define DH_ 64
#define MROWS_ (B_*S_)   // 8192

static __device__ __forceinline__ float frcp(float x){ return __builtin_amdgcn_rcpf(x); }
static __device__ __forceinline__ float fsigm(float x){ return frcp(1.0f + __expf(-x)); }
static __device__ __forceinline__ float flogsig(float x){
    return fminf(x, 0.f) - __logf(1.0f + __expf(-fabsf(x)));
}
static __device__ __forceinline__ float ftanh(float z){
    return 1.0f - 2.0f*frcp(__expf(2.0f*z) + 1.0f);
}

// ---------------- Tiled GEMM: C = A @ W^T + bias (+ res) ----------------
__global__ __launch_bounds__(256, 2) void gemm_bias_big(
        const float* __restrict__ A, const float* __restrict__ W,
        const float* __restrict__ bias, const float* __restrict__ res,
        float* __restrict__ C, int M, int N, int K) {
    __shared__ float As[64*68];
    __shared__ float Ws[64*68];
    int tid = threadIdx.x;
    int wid = tid >> 6, lane = tid & 63;
    int wy = wid >> 1, wx = wid & 1;
    int sg = lane >> 3, tg = lane & 7;
    int m0 = blockIdx.y*64, n0 = blockIdx.x*64;
    int r = tid >> 2, c0 = (tid & 3) << 4;
    bool vec = ((K & 3) == 0);
    float acc[4][4];
    #pragma unroll
    for (int i = 0; i < 4; ++i)
        #pragma unroll
        for (int j = 0; j < 4; ++j) acc[i][j] = 0.f;

    for (int k0 = 0; k0 < K; k0 += 64) {
        __syncthreads();
        const float* Ar = A + (size_t)(m0+r)*K + k0;
        const float* Wr = W + (size_t)(n0+r)*K + k0;
        if (vec) {
            #pragma unroll
            for (int i = 0; i < 4; ++i) {
                *(float4*)(&As[r*68 + c0 + 4*i]) = *(const float4*)(Ar + c0 + 4*i);
                *(float4*)(&Ws[r*68 + c0 + 4*i]) = *(const float4*)(Wr + c0 + 4*i);
            }
        } else {
            #pragma unroll
            for (int i = 0; i < 4; ++i)
                #pragma unroll
                for (int e = 0; e < 4; ++e) {
                    int c = c0 + 4*i + e;
                    bool ok = (k0 + c) < K;
                    As[r*68 + c] = ok ? Ar[c] : 0.f;
                    Ws[r*68 + c] = ok ? Wr[c] : 0.f;
                }
        }
        __syncthreads();
        const float* arow = &As[(32*wy + sg)*68];
        const float* brow = &Ws[(32*wx + tg)*68];
        #pragma unroll 2
        for (int d = 0; d < 64; d += 4) {
            float4 b0 = *(const float4*)(brow + 0*544 + d);
            float4 b1 = *(const float4*)(brow + 1*544 + d);
            float4 b2 = *(const float4*)(brow + 2*544 + d);
            float4 b3 = *(const float4*)(brow + 3*544 + d);
            #pragma unroll
            for (int i = 0; i < 4; ++i) {
                float4 a = *(const float4*)(arow + i*544 + d);
                acc[i][0] += a.x*b0.x + a.y*b0.y + a.z*b0.z + a.w*b0.w;
                acc[i][1] += a.x*b1.x + a.y*b1.y + a.z*b1.z + a.w*b1.w;
                acc[i][2] += a.x*b2.x + a.y*b2.y + a.z*b2.z + a.w*b2.w;
                acc[i][3] += a.x*b3.x + a.y*b3.y + a.z*b3.z + a.w*b3.w;
            }
        }
    }
    #pragma unroll
    for (int i = 0; i < 4; ++i) {
        int m = m0 + 32*wy + 8*i + sg;
        #pragma unroll
        for (int j = 0; j < 4; ++j) {
            int n = n0 + 32*wx + 8*j + tg;
            float v = acc[i][j] + bias[n];
            if (res) v += res[(size_t)m*N + n];
            C[(size_t)m*N + n] = v;
        }
    }
}

// ---------------- FUSED GEMM (N=128) + LayerNorm epilogue, 32-row tiles ----------------
__global__ __launch_bounds__(256, 2) void gemm_ln(
        const float* __restrict__ A, const float* __restrict__ W,
        const float* __restrict__ bias, const float* __restrict__ res,
        const float* __restrict__ lnw, float* __restrict__ H,
        float* __restrict__ Rout, int M, int K) {
    __shared__ float As[32*68];
    __shared__ float Ws[128*68];
    __shared__ float Lsum[2][32], Lssq[2][32];
    int tid = threadIdx.x;
    int wid = tid >> 6, lane = tid & 63;
    int wy = wid >> 1, wx = wid & 1;
    int sg = lane >> 3, tg = lane & 7;
    int m0 = blockIdx.x*32;
    int ra = tid >> 3, ca0 = (tid & 7) << 3;
    int rw = tid >> 1, cw0 = (tid & 1) << 5;
    bool vec = ((K & 3) == 0);
    float acc[2][8];
    #pragma unroll
    for (int i = 0; i < 2; ++i)
        #pragma unroll
        for (int j = 0; j < 8; ++j) acc[i][j] = 0.f;

    for (int k0 = 0; k0 < K; k0 += 64) {
        __syncthreads();
        const float* Ar = A + (size_t)(m0+ra)*K + k0;
        const float* Wr = W + (size_t)rw*K + k0;
        if (vec) {
            *(float4*)(&As[ra*68 + ca0])     = *(const float4*)(Ar + ca0);
            *(float4*)(&As[ra*68 + ca0 + 4]) = *(const float4*)(Ar + ca0 + 4);
            #pragma unroll
            for (int i = 0; i < 8; ++i)
                *(float4*)(&Ws[rw*68 + cw0 + 4*i]) = *(const float4*)(Wr + cw0 + 4*i);
        } else {
            #pragma unroll
            for (int e = 0; e < 8; ++e) {
                int c = ca0 + e;
                As[ra*68 + c] = ((k0 + c) < K) ? Ar[c] : 0.f;
            }
            #pragma unroll
            for (int i = 0; i < 8; ++i)
                #pragma unroll
                for (int e = 0; e < 4; ++e) {
                    int c = cw0 + 4*i + e;
                    Ws[rw*68 + c] = ((k0 + c) < K) ? Wr[c] : 0.f;
                }
        }
        __syncthreads();
        const float* arow0 = &As[(16*wy + sg)*68];
        const float* arow1 = arow0 + 8*68;
        const float* brow  = &Ws[(64*wx + tg)*68];
        #pragma unroll 1
        for (int d = 0; d < 64; d += 4) {
            float4 a0 = *(const float4*)(arow0 + d);
            float4 a1 = *(const float4*)(arow1 + d);
            #pragma unroll
            for (int j = 0; j < 8; ++j) {
                float4 b = *(const float4*)(brow + j*544 + d);
                acc[0][j] += a0.x*b.x + a0.y*b.y + a0.z*b.z + a0.w*b.w;
                acc[1][j] += a1.x*b.x + a1.y*b.y + a1.z*b.z + a1.w*b.w;
            }
        }
    }
    float ps[2], pss[2];
    #pragma unroll
    for (int i = 0; i < 2; ++i) {
        int m = m0 + 16*wy + 8*i + sg;
        float s = 0.f, ss = 0.f;
        #pragma unroll
        for (int j = 0; j < 8; ++j) {
            int n = 64*wx + 8*j + tg;
            float vv = acc[i][j] + bias[n];
            if (res) vv += res[(size_t)m*128 + n];
            acc[i][j] = vv;
            s += vv; ss += vv*vv;
        }
        ps[i] = s; pss[i] = ss;
    }
    #pragma unroll
    for (int bm = 1; bm <= 4; bm <<= 1)
        #pragma unroll
        for (int i = 0; i < 2; ++i) {
            ps[i]  += __shfl_xor(ps[i],  bm, 64);
            pss[i] += __shfl_xor(pss[i], bm, 64);
        }
    if (tg == 0) {
        #pragma unroll
        for (int i = 0; i < 2; ++i) {
            int rloc = 16*wy + 8*i + sg;
            Lsum[wx][rloc] = ps[i];
            Lssq[wx][rloc] = pss[i];
        }
    }
    __syncthreads();
    #pragma unroll
    for (int i = 0; i < 2; ++i) {
        int rloc = 16*wy + 8*i + sg;
        int m = m0 + rloc;
        float s  = Lsum[0][rloc] + Lsum[1][rloc];
        float ss = Lssq[0][rloc] + Lssq[1][rloc];
        float mu = s*(1.f/128.f);
        float var = ss*(1.f/128.f) - mu*mu;
        float inv = rsqrtf(var + 1e-5f);
        #pragma unroll
        for (int j = 0; j < 8; ++j) {
            int n = 64*wx + 8*j + tg;
            float vv = acc[i][j];
            H[(size_t)m*128 + n]    = vv;
            Rout[(size_t)m*128 + n] = (vv-mu)*inv*lnw[n];
        }
    }
}

// ---------------- FUSED FFN up-GEMM + gelu(g)*u2 epilogue ----------------
__global__ __launch_bounds__(256, 2) void gemm_ffn_act(
        const float* __restrict__ A, const float* __restrict__ Wu,
        const float* __restrict__ bu, float* __restrict__ act, int M) {
    __shared__ float As[64*68];
    __shared__ float Wg[64*68];
    __shared__ float Wu2[64*68];
    int tid = threadIdx.x;
    int wid = tid >> 6, lane = tid & 63;
    int wy = wid >> 1, wx = wid & 1;
    int sg = lane >> 3, tg = lane & 7;
    int m0 = blockIdx.y*64, nb = blockIdx.x*64;
    int r = tid >> 2, c0 = (tid & 3) << 4;
    float ag[4][4], au[4][4];
    #pragma unroll
    for (int i = 0; i < 4; ++i)
        #pragma unroll
        for (int j = 0; j < 4; ++j) { ag[i][j] = 0.f; au[i][j] = 0.f; }

    for (int k0 = 0; k0 < 128; k0 += 64) {
        __syncthreads();
        const float* Ar = A + (size_t)(m0+r)*128 + k0;
        const float* Wgr = Wu + (size_t)(nb+r)*128 + k0;
        const float* Wur = Wu + (size_t)(192+nb+r)*128 + k0;
        #pragma unroll
        for (int i = 0; i < 4; ++i) {
            *(float4*)(&As[r*68 + c0 + 4*i])  = *(const float4*)(Ar + c0 + 4*i);
            *(float4*)(&Wg[r*68 + c0 + 4*i])  = *(const float4*)(Wgr + c0 + 4*i);
            *(float4*)(&Wu2[r*68 + c0 + 4*i]) = *(const float4*)(Wur + c0 + 4*i);
        }
        __syncthreads();
        const float* arow = &As[(32*wy + sg)*68];
        const float* grow = &Wg[(32*wx + tg)*68];
        const float* urow = &Wu2[(32*wx + tg)*68];
        #pragma unroll 2
        for (int d = 0; d < 64; d += 4) {
            float4 g0 = *(const float4*)(grow + 0*544 + d);
            float4 g1 = *(const float4*)(grow + 1*544 + d);
            float4 g2 = *(const float4*)(grow + 2*544 + d);
            float4 g3 = *(const float4*)(grow + 3*544 + d);
            float4 u0 = *(const float4*)(urow + 0*544 + d);
            float4 u1 = *(const float4*)(urow + 1*544 + d);
            float4 u2 = *(const float4*)(urow + 2*544 + d);
            float4 u3 = *(const float4*)(urow + 3*544 + d);
            #pragma unroll
            for (int i = 0; i < 4; ++i) {
                float4 a = *(const float4*)(arow + i*544 + d);
                ag[i][0] += a.x*g0.x + a.y*g0.y + a.z*g0.z + a.w*g0.w;
                ag[i][1] += a.x*g1.x + a.y*g1.y + a.z*g1.z + a.w*g1.w;
                ag[i][2] += a.x*g2.x + a.y*g2.y + a.z*g2.z + a.w*g2.w;
                ag[i][3] += a.x*g3.x + a.y*g3.y + a.z*g3.z + a.w*g3.w;
                au[i][0] += a.x*u0.x + a.y*u0.y + a.z*u0.z + a.w*u0.w;
                au[i][1] += a.x*u1.x + a.y*u1.y + a.z*u1.z + a.w*u1.w;
                au[i][2] += a.x*u2.x + a.y*u2.y + a.z*u2.z + a.w*u2.w;
                au[i][3] += a.x*u3.x + a.y*u3.y + a.z*u3.z + a.w*u3.w;
            }
        }
    }
    #pragma unroll
    for (int i = 0; i < 4; ++i) {
        int m = m0 + 32*wy + 8*i + sg;
        #pragma unroll
        for (int j = 0; j < 4; ++j) {
            int n = nb + 32*wx + 8*j + tg;
            float g  = ag[i][j] + bu[n];
            float u2 = au[i][j] + bu[192+n];
            float ge = 0.5f*g*(1.0f + erff(g*0.70710678118f));
            act[(size_t)m*192 + n] = ge*u2;
        }
    }
}

// ---------------- FUSED mLSTM front-end: conv+silu, q/k/v headwise, gateproj ----------------
__global__ __launch_bounds__(64) void mlstm_qkv(
        const float* __restrict__ up, const float* __restrict__ convk,
        const float* __restrict__ convb,
        const float* __restrict__ Wq, const float* __restrict__ bq,
        const float* __restrict__ Wk, const float* __restrict__ bk,
        const float* __restrict__ Wv, const float* __restrict__ bv,
        const float* __restrict__ Wig, const float* __restrict__ big,
        const float* __restrict__ Wfg, const float* __restrict__ bfg,
        float* __restrict__ xc, float* __restrict__ q, float* __restrict__ k,
        float* __restrict__ v, float* __restrict__ igp, float* __restrict__ fgp) {
    int row = blockIdx.x;
    int b = row >> 10, s = row & 1023;
    int l = threadIdx.x;
    int c0 = l*4;
    float4 xm[4];
    #pragma unroll
    for (int i = 0; i < 4; ++i) {
        int sp = s - 3 + i;
        if (sp >= 0) xm[i] = *(const float4*)(up + (size_t)(row-3+i)*512 + c0);
        else         xm[i] = make_float4(0.f,0.f,0.f,0.f);
    }
    float xcv[4];
    #pragma unroll
    for (int j = 0; j < 4; ++j) {
        int c = c0 + j;
        float acc = convb[c];
        #pragma unroll
        for (int i = 0; i < 4; ++i)
            acc += ((const float*)&xm[i])[j] * convk[c*4+i];
        xcv[j] = acc * fsigm(acc);
    }
    *(float4*)(xc + (size_t)row*256 + c0) = make_float4(xcv[0],xcv[1],xcv[2],xcv[3]);
    float qv[4], kv[4], vv[4];
    #pragma unroll
    for (int o = 0; o < 4; ++o) {
        const float* wq = Wq + ((size_t)l*4 + o)*4;
        const float* wk = Wk + ((size_t)l*4 + o)*4;
        const float* wv = Wv + ((size_t)l*4 + o)*4;
        float aq = bq[c0+o], ak = bk[c0+o], avv = bv[c0+o];
        #pragma unroll
        for (int i = 0; i < 4; ++i) {
            aq  += xcv[i]*wq[i];
            ak  += xcv[i]*wk[i];
            avv += ((const float*)&xm[3])[i]*wv[i];
        }
        qv[o]=aq; kv[o]=ak; vv[o]=avv;
    }
    *(float4*)(q + (size_t)row*256 + c0) = make_float4(qv[0],qv[1],qv[2],qv[3]);
    *(float4*)(k + (size_t)row*256 + c0) = make_float4(kv[0],kv[1],kv[2],kv[3]);
    *(float4*)(v + (size_t)row*256 + c0) = make_float4(vv[0],vv[1],vv[2],vv[3]);
    float dots[8];
    #pragma unroll
    for (int g = 0; g < 4; ++g) {
        float di = 0.f, df = 0.f;
        #pragma unroll
        for (int j = 0; j < 4; ++j) {
            di += qv[j]*Wig[g*768 + c0 + j] + kv[j]*Wig[g*768 + 256 + c0 + j]
                + vv[j]*Wig[g*768 + 512 + c0 + j];
            df += qv[j]*Wfg[g*768 + c0 + j] + kv[j]*Wfg[g*768 + 256 + c0 + j]
                + vv[j]*Wfg[g*768 + 512 + c0 + j];
        }
        dots[g] = di; dots[4+g] = df;
    }
    #pragma unroll
    for (int off = 32; off > 0; off >>= 1)
        #pragma unroll
        for (int g = 0; g < 8; ++g) dots[g] += __shfl_down(dots[g], off, 64);
    if (l == 0) {
        #pragma unroll
        for (int g = 0; g < 4; ++g) {
            igp[((size_t)b*NH_+g)*S_ + s] = dots[g]   + big[g];
            fgp[((size_t)b*NH_+g)*S_ + s] = dots[4+g] + bfg[g];
        }
    }
}

// ---------------- FUSED sLSTM front-end: conv+silu + all-4-gate matvecs ----------------
__global__ __launch_bounds__(128) void slstm_convgates(
        const float* __restrict__ r, const float* __restrict__ convk,
        const float* __restrict__ convb, const float* __restrict__ Wi,
        const float* __restrict__ Wf, const float* __restrict__ Wz,
        const float* __restrict__ Wo, float* __restrict__ GX) {
    int row = blockIdx.x; int s = row & 1023;
    int c = threadIdx.x;
    __shared__ float rcL[128], rL[128];
    float rv = r[(size_t)row*128 + c];
    float acc = convb[c];
    #pragma unroll
    for (int i = 0; i < 4; ++i) {
        int sp = s - 3 + i;
        if (sp >= 0) acc += r[(size_t)(row-3+i)*128 + c]*convk[c*4+i];
    }
    float rcv = acc * fsigm(acc);
    rcL[c] = rcv; rL[c] = rv;
    __syncthreads();
    int h = c >> 5, o = c & 31;
    size_t wb = ((size_t)h*32 + o)*32;
    const float* rc_ = rcL + h*32;
    const float* rr_ = rL + h*32;
    float di=0.f, df=0.f, dz=0.f, doo=0.f;
    #pragma unroll
    for (int i = 0; i < 32; ++i) {
        float a = rc_[i], cc = rr_[i];
        di  += a*Wi[wb+i];
        df  += a*Wf[wb+i];
        dz  += cc*Wz[wb+i];
        doo += cc*Wo[wb+i];
    }
    float* g = GX + (size_t)row*512 + h*128 + o;
    g[0]  = di;
    g[32] = df;
    g[64] = dz;
    g[96] = doo;
}

// ---------------- mLSTM decay precompute ----------------
__global__ void mlstm_scan_pre(const float* __restrict__ igp, const float* __restrict__ fgp,
                               float* __restrict__ lc, float* __restrict__ av,
                               float* __restrict__ mx) {
    int bh = blockIdx.x; int t = threadIdx.x;  // 1024 threads
    __shared__ float buf[2][1024];
    float ls = flogsig(fgp[(size_t)bh*S_ + t]);
    int cur = 0;
    buf[0][t] = ls; __syncthreads();
    for (int off=1; off<1024; off<<=1) {
        float x2 = buf[cur][t];
        if (t >= off) x2 += buf[cur][t-off];
        buf[cur^1][t] = x2; cur ^= 1; __syncthreads();
    }
    float lcv = buf[cur][t];
    lc[(size_t)bh*S_+t] = lcv;
    float a = igp[(size_t)bh*S_+t] - lcv;
    av[(size_t)bh*S_+t] = a;
    __syncthreads();
    cur = 0; buf[0][t] = a; __syncthreads();
    for (int off=1; off<1024; off<<=1) {
        float x2 = buf[cur][t];
        if (t >= off) x2 = fmaxf(x2, buf[cur][t-off]);
        buf[cur^1][t] = x2; cur ^= 1; __syncthreads();
    }
    mx[(size_t)bh*S_+t] = buf[cur][t];
}

// ---------------- mLSTM attention + FUSED mh-LN/skip/gate epilogue ----------------
// Epilogue: group LN over the block's own 64 channels (exactly head hh) via
// tg-butterfly + cross-wx LDS combine (reusing qs as scratch), then
// hs = (LN(hc)*onw + skip*xc) * silu(z). mlstm_out kernel eliminated.
__global__ __launch_bounds__(256, 3) void mlstm_attn_tiled(
        const float* __restrict__ q, const float* __restrict__ k,
        const float* __restrict__ v, const float* __restrict__ lc,
        const float* __restrict__ av, const float* __restrict__ mx,
        const float* __restrict__ xc, const float* __restrict__ up,
        const float* __restrict__ onw, const float* __restrict__ skip,
        float* __restrict__ hs) {
    int bid = blockIdx.x;
    int stile = 15 - (bid & 15);
    int bh = bid >> 4;
    int hh = bh & 3, b = bh >> 2;
    int s0 = stile << 6;
    int tid = threadIdx.x;
    int wid = tid >> 6, lane = tid & 63;
    int wy = wid >> 1, wx = wid & 1;
    int sg = lane >> 3, tg = lane & 7;

    __shared__ float qs[64*68];
    __shared__ float kst[64*68];
    __shared__ float vtT[64*68];
    __shared__ float avt[64], maxsL[64], normL[64], rsumL[128];

    const size_t bhS = (size_t)bh * S_;
    {
        int r = tid >> 2, c0 = (tid & 3) << 4;
        const float* qg = q + ((size_t)(b*S_) + s0 + r)*INNER_ + hh*64;
        #pragma unroll
        for (int i = 0; i < 4; ++i) {
            float4 t4 = *(const float4*)(qg + c0 + 4*i);
            float4 w4; w4.x=t4.x*0.125f; w4.y=t4.y*0.125f; w4.z=t4.z*0.125f; w4.w=t4.w*0.125f;
            *(float4*)(&qs[r*68 + c0 + 4*i]) = w4;
        }
        if (tid < 64) maxsL[tid] = lc[bhS + s0 + tid] + mx[bhS + s0 + tid];
    }
    float msv[4];
    #pragma unroll
    for (int i = 0; i < 4; ++i)
        msv[i] = mx[bhS + s0 + 32*wy + 8*i + sg];

    float O[4][4];
    float rsAcc[4];
    #pragma unroll
    for (int i = 0; i < 4; ++i) {
        rsAcc[i] = 0.f;
        #pragma unroll
        for (int j = 0; j < 4; ++j) O[i][j] = 0.f;
    }

    for (int t0 = 0; t0 <= s0; t0 += 64) {
        __syncthreads();
        {
            int r = tid >> 2, c0 = (tid & 3) << 4;
            const float* kg = k + ((size_t)(b*S_) + t0 + r)*INNER_ + hh*64;
            const float* vg = v + ((size_t)(b*S_) + t0 + r)*INNER_ + hh*64;
            #pragma unroll
            for (int i = 0; i < 4; ++i) {
                *(float4*)(&kst[r*68 + c0 + 4*i]) = *(const float4*)(kg + c0 + 4*i);
                float4 v4 = *(const float4*)(vg + c0 + 4*i);
                int dc = c0 + 4*i;
                vtT[(dc+0)*68 + r] = v4.x;
                vtT[(dc+1)*68 + r] = v4.y;
                vtT[(dc+2)*68 + r] = v4.z;
                vtT[(dc+3)*68 + r] = v4.w;
            }
            if (tid < 64) avt[tid] = av[bhS + t0 + tid];
        }
        __syncthreads();
        float dot[4][4];
        #pragma unroll
        for (int i = 0; i < 4; ++i)
            #pragma unroll
            for (int j = 0; j < 4; ++j) dot[i][j] = 0.f;
        {
            const float* qrow = &qs[(32*wy + sg)*68];
            const float* krow = &kst[(32*wx + tg)*68];
            #pragma unroll 2
            for (int d = 0; d < 64; d += 4) {
                float4 b0 = *(const float4*)(krow + 0*544 + d);
                float4 b1 = *(const float4*)(krow + 1*544 + d);
                float4 b2 = *(const float4*)(krow + 2*544 + d);
                float4 b3 = *(const float4*)(krow + 3*544 + d);
                #pragma unroll
                for (int i = 0; i < 4; ++i) {
                    float4 a = *(const float4*)(qrow + i*544 + d);
                    dot[i][0] += a.x*b0.x + a.y*b0.y + a.z*b0.z + a.w*b0.w;
                    dot[i][1] += a.x*b1.x + a.y*b1.y + a.z*b1.z + a.w*b1.w;
                    dot[i][2] += a.x*b2.x + a.y*b2.y + a.z*b2.z + a.w*b2.w;
                    dot[i][3] += a.x*b3.x + a.y*b3.y + a.z*b3.z + a.w*b3.w;
                }
            }
        }
        __syncthreads();
        #pragma unroll
        for (int i = 0; i < 4; ++i) {
            int s_loc = 32*wy + 8*i + sg;
            float rp = 0.f;
            #pragma unroll
            for (int j = 0; j < 4; ++j) {
                int t_loc = 32*wx + 8*j + tg;
                bool ok = (t0 + t_loc) <= (s0 + s_loc);
                float p = ok ? dot[i][j]*__expf(avt[t_loc] - msv[i]) : 0.f;
                kst[s_loc*68 + t_loc] = p;
                rp += p;
            }
            rp += __shfl_xor(rp, 1);
            rp += __shfl_xor(rp, 2);
            rp += __shfl_xor(rp, 4);
            rsAcc[i] += rp;
        }
        __syncthreads();
        {
            const float* prow = &kst[(32*wy + sg)*68];
            const float* vrow = &vtT[(32*wx + tg)*68];
            #pragma unroll 2
            for (int tt = 0; tt < 64; tt += 4) {
                float4 b0 = *(const float4*)(vrow + 0*544 + tt);
                float4 b1 = *(const float4*)(vrow + 1*544 + tt);
                float4 b2 = *(const float4*)(vrow + 2*544 + tt);
                float4 b3 = *(const float4*)(vrow + 3*544 + tt);
                #pragma unroll
                for (int i = 0; i < 4; ++i) {
                    float4 a = *(const float4*)(prow + i*544 + tt);
                    O[i][0] += a.x*b0.x + a.y*b0.y + a.z*b0.z + a.w*b0.w;
                    O[i][1] += a.x*b1.x + a.y*b1.y + a.z*b1.z + a.w*b1.w;
                    O[i][2] += a.x*b2.x + a.y*b2.y + a.z*b2.z + a.w*b2.w;
                    O[i][3] += a.x*b3.x + a.y*b3.y + a.z*b3.z + a.w*b3.w;
                }
            }
        }
    }
    if (tg == 0) {
        #pragma unroll
        for (int i = 0; i < 4; ++i)
            rsumL[wx*64 + 32*wy + 8*i + sg] = rsAcc[i];
    }
    __syncthreads();
    if (tid < 64) {
        float tot = rsumL[tid] + rsumL[64 + tid];
        normL[tid] = fmaxf(fabsf(tot), __expf(-maxsL[tid])) + 1e-6f;
    }
    __syncthreads();
    // ---- fused mh-LN + skip + gate epilogue ----
    float ls_[4], lq_[4];
    #pragma unroll
    for (int i = 0; i < 4; ++i) {
        int s_loc = 32*wy + 8*i + sg;
        float inv = frcp(normL[s_loc]);
        float s = 0.f, ss = 0.f;
        #pragma unroll
        for (int j = 0; j < 4; ++j) {
            float vv = O[i][j]*inv;
            O[i][j] = vv;
            s += vv; ss += vv*vv;
        }
        ls_[i] = s; lq_[i] = ss;
    }
    #pragma unroll
    for (int bm = 1; bm <= 4; bm <<= 1)
        #pragma unroll
        for (int i = 0; i < 4; ++i) {
            ls_[i] += __shfl_xor(ls_[i], bm, 64);
            lq_[i] += __shfl_xor(lq_[i], bm, 64);
        }
    float* Ls = qs;            // reuse (all qs reads complete past 2 barriers)
    float* Lq = qs + 128;
    if (tg == 0) {
        #pragma unroll
        for (int i = 0; i < 4; ++i) {
            int s_loc = 32*wy + 8*i + sg;
            Ls[wx*64 + s_loc] = ls_[i];
            Lq[wx*64 + s_loc] = lq_[i];
        }
    }
    __syncthreads();
    #pragma unroll
    for (int i = 0; i < 4; ++i) {
        int s_loc = 32*wy + 8*i + sg;
        size_t row = (size_t)(b*S_) + s0 + s_loc;
        float s  = Ls[s_loc] + Ls[64 + s_loc];
        float ss = Lq[s_loc] + Lq[64 + s_loc];
        float mu = s*(1.f/64.f);
        float var = ss*(1.f/64.f) - mu*mu;
        float linv = rsqrtf(var + 1e-5f);
        #pragma unroll
        for (int j = 0; j < 4; ++j) {
            int ch = hh*64 + 32*wx + 8*j + tg;
            float ht = (O[i][j]-mu)*linv*onw[ch];
            float z  = up[row*512 + 256 + ch];
            float xv = xc[row*256 + ch];
            hs[row*256 + ch] = (ht + skip[ch]*xv) * (z*fsigm(z));
        }
    }
}

// ---------------- sLSTM scan: pair-lane layout, DPP gate exchange ----------------
__global__ __launch_bounds__(64, 1) void slstm_scan_wave(
        const float* __restrict__ gx, const float* __restrict__ R,
        const float* __restrict__ bb, float* __restrict__ ys) {
    int blk = blockIdx.x; int hh = blk & 3; int b = blk >> 2;
    int l = threadIdx.x;  // 0..63
    int e = l >> 1, p = l & 1;
    int o0 = p*32 + e, o1 = (p+2)*32 + e;
    float Rc0[32], Rc1[32];
    #pragma unroll
    for (int d = 0; d < 32; ++d) {
        Rc0[d] = R[(size_t)(hh*32 + d)*128 + o0];
        Rc1[d] = R[(size_t)(hh*32 + d)*128 + o1];
        asm volatile("" : "+v"(Rc0[d]));
        asm volatile("" : "+v"(Rc1[d]));
    }
    float bj0 = bb[hh*128 + o0], bj1 = bb[hh*128 + o1];
    float cst = 0.f, nst = 0.f, mst = 0.f, y = 0.f;
    const float* gbase = gx + (size_t)(b*S_)*512 + hh*128;
    float* ybase = ys + (size_t)(b*S_)*128 + hh*32 + e;
    float ga[4], gb[4];
    #pragma unroll
    for (int u = 0; u < 4; ++u) {
        ga[u] = gbase[(size_t)u*512 + o0];
        gb[u] = gbase[(size_t)u*512 + o1];
    }
    for (int t = 0; t < S_; t += 4) {
        float gna[4], gnb[4];
        #pragma unroll
        for (int u = 0; u < 4; ++u) {
            int tn = t + 4 + u;
            size_t off = (size_t)(tn < S_ ? tn : 0) * 512;
            gna[u] = gbase[off + o0];
            gnb[u] = gbase[off + o1];
        }
        #pragma unroll
        for (int u = 0; u < 4; ++u) {
            float a0=0.f, a1=0.f, a2=0.f, a3=0.f;
            float c0=0.f, c1=0.f, c2=0.f, c3=0.f;
            #pragma unroll
            for (int d = 0; d < 32; d += 4) {
                float y0 = __int_as_float(__builtin_amdgcn_readlane(__float_as_int(y), 2*d));
                float y1 = __int_as_float(__builtin_amdgcn_readlane(__float_as_int(y), 2*d+2));
                float y2 = __int_as_float(__builtin_amdgcn_readlane(__float_as_int(y), 2*d+4));
                float y3 = __int_as_float(__builtin_amdgcn_readlane(__float_as_int(y), 2*d+6));
                a0 += y0*Rc0[d];   c0 += y0*Rc1[d];
                a1 += y1*Rc0[d+1]; c1 += y1*Rc1[d+1];
                a2 += y2*Rc0[d+2]; c2 += y2*Rc1[d+2];
                a3 += y3*Rc0[d+3]; c3 += y3*Rc1[d+3];
            }
            float r0 = ga[u] + bj0 + ((a0+a1)+(a2+a3));
            float r1 = gb[u] + bj1 + ((c0+c1)+(c2+c3));
            float fo0 = __int_as_float(__builtin_amdgcn_mov_dpp(__float_as_int(r0), 0xB1, 0xF, 0xF, true));
            float fo1 = __int_as_float(__builtin_amdgcn_mov_dpp(__float_as_int(r1), 0xB1, 0xF, 0xF, true));
            float iraw = p ? fo0 : r0;
            float fraw = p ? r0 : fo0;
            float zraw = p ? fo1 : r1;
            float oraw = p ? r1 : fo1;
            int t_abs = t + u;
            float lfm = mst + flogsig(fraw);
            float mnew = (t_abs == 0) ? iraw : fmaxf(iraw, lfm);
            float igv = __expf(iraw - mnew), fgv = __expf(lfm - mnew);
            cst = fgv*cst + igv*ftanh(zraw);
            nst = fgv*nst + igv;
            mst = mnew;
            y = cst * frcp(nst * (1.0f + __expf(-oraw)));
            if (p == 0) ybase[(size_t)t_abs*128] = y;
        }
        #pragma unroll
        for (int u = 0; u < 4; ++u) { ga[u] = gna[u]; gb[u] = gnb[u]; }
    }
}

// ---------------- FUSED: h += mh_ln(ys; GS=32)*gnw ; r = LN(h)*ffn_nw ----------------
__global__ void slstm_addnorm_ln(const float* __restrict__ ys, const float* __restrict__ gnw,
                                 const float* __restrict__ ffnw,
                                 float* __restrict__ h, float* __restrict__ r) {
    int row = blockIdx.x; int c = threadIdx.x;  // 128
    __shared__ float s1[128], s2[128];
    float v = ys[(size_t)row*128 + c];
    s1[c]=v; s2[c]=v*v; __syncthreads();
    int li = c & 31;
    for (int off=16; off>0; off>>=1){
        if (li < off){ s1[c]+=s1[c+off]; s2[c]+=s2[c+off]; }
        __syncthreads();
    }
    int base = c & ~31;
    float mu = s1[base]*(1.f/32.f);
    float var = s2[base]*(1.f/32.f) - mu*mu;
    float hn = h[(size_t)row*128 + c] + (v-mu)*rsqrtf(var+1e-5f)*gnw[c];
    h[(size_t)row*128 + c] = hn;
    __syncthreads();
    s1[c]=hn; s2[c]=hn*hn; __syncthreads();
    for (int off=64; off>0; off>>=1){
        if (c<off){ s1[c]+=s1[c+off]; s2[c]+=s2[c+off]; }
        __syncthreads();
    }
    float mu2 = s1[0]*(1.f/128.f);
    float var2 = s2[0]*(1.f/128.f) - mu2*mu2;
    r[(size_t)row*128 + c] = (hn-mu2)*rsqrtf(var2+1e-5f)*ffnw[c];
}

// ---------------- FUSED final: LN(last-token rows only) + FC ----------------
__global__ void final_ln_fc(const float* __restrict__ h, const float* __restrict__ postw,
                            const float* __restrict__ fcW, const float* __restrict__ fcb,
                            float* __restrict__ out) {
    int b = blockIdx.x; int t = threadIdx.x;  // 128
    const float* hr = h + (size_t)(b*S_ + S_-1)*128;
    float v = hr[t];
    __shared__ float s1[128], s2[128];
    s1[t]=v; s2[t]=v*v; __syncthreads();
    for (int off=64; off>0; off>>=1){
        if (t<off){ s1[t]+=s1[t+off]; s2[t]+=s2[t+off]; }
        __syncthreads();
    }
    float mu = s1[0]*(1.f/128.f);
    float var = s2[0]*(1.f/128.f) - mu*mu;
    float hp = (v-mu)*rsqrtf(var+1e-5f)*postw[t];
    __syncthreads();
    s1[t] = hp*fcW[t]; __syncthreads();
    for (int off=64; off>0; off>>=1){
        if (t<off) s1[t]+=s1[t+off];
        __syncthreads();
    }
    if (t == 0) out[b] = s1[0] + fcb[0];
}

extern "C" void kernel_launch(void* const* d_in, const int* in_sizes, int n_in,
                              void* d_out, int out_size, void* d_ws, size_t ws_size,
                              hipStream_t stream) {
    const float* x       = (const float*)d_in[0];
    const float* W_in    = (const float*)d_in[1];
    const float* b_in    = (const float*)d_in[2];
    const float* ln0_w   = (const float*)d_in[3];
    const float* m_Wup   = (const float*)d_in[4];
    const float* m_bup   = (const float*)d_in[5];
    const float* m_convk = (const float*)d_in[6];
    const float* m_convb = (const float*)d_in[7];
    const float* m_Wq    = (const float*)d_in[8];
    const float* m_bq    = (const float*)d_in[9];
    const float* m_Wk    = (const float*)d_in[10];
    const float* m_bk    = (const float*)d_in[11];
    const float* m_Wv    = (const float*)d_in[12];
    const float* m_bv    = (const float*)d_in[13];
    const float* m_Wig   = (const float*)d_in[14];
    const float* m_big   = (const float*)d_in[15];
    const float* m_Wfg   = (const float*)d_in[16];
    const float* m_bfg   = (const float*)d_in[17];
    const float* m_onw   = (const float*)d_in[18];
    const float* m_skip  = (const float*)d_in[19];
    const float* m_Wd    = (const float*)d_in[20];
    const float* m_bd    = (const float*)d_in[21];
    const float* ln1_w   = (const float*)d_in[22];
    const float* s_convk = (const float*)d_in[23];
    const float* s_convb = (const float*)d_in[24];
    const float* s_Wi    = (const float*)d_in[25];
    const float* s_Wf    = (const float*)d_in[26];
    const float* s_Wz    = (const float*)d_in[27];
    const float* s_Wo    = (const float*)d_in[28];
    const float* s_R     = (const float*)d_in[29];
    const float* s_b     = (const float*)d_in[30];
    const float* s_gnw   = (const float*)d_in[31];
    const float* ffn_nw  = (const float*)d_in[32];
    const float* f_Wu    = (const float*)d_in[33];
    const float* f_bu    = (const float*)d_in[34];
    const float* f_Wd    = (const float*)d_in[35];
    const float* f_bd    = (const float*)d_in[36];
    const float* post_w  = (const float*)d_in[37];
    const float* fc_W    = (const float*)d_in[38];
    const float* fc_b    = (const float*)d_in[39];
    float* out = (float*)d_out;

    float* W = (float*)d_ws;
    const size_t M1 = 1048576;        // 8192*128
    float* h    = W;                   // 1M
    float* r    = W + 1*M1;            // 1M
    float* up   = W + 2*M1;            // 4M
    float* xc   = W + 6*M1;            // 2M
    float* q    = W + 8*M1;            // 2M
    float* kbuf = W + 10*M1;           // 2M
    float* vbuf = W + 12*M1;           // 2M
    float* hc   = W + 14*M1;           // 2M  (hs now lives here)
    float* igp  = W + 16*M1;
    float* fgp  = igp + 32768;
    float* lc   = fgp + 32768;
    float* av   = lc  + 32768;
    float* mx   = av  + 32768;
    float* hs   = hc;                  // attention writes hs directly (q still live)
    float* gx   = kbuf;
    float* ys   = q;                   // q dead after attention
    float* act  = q;                   // ys dead after addnorm_ln

    // 1. h = x @ W_in^T + b_in ; r = LN(h)*ln0_w
    gemm_ln<<<MROWS_/32, 256, 0, stream>>>(x, W_in, b_in, nullptr, ln0_w, h, r, MROWS_, F_);
    // 2. up = r @ m_Wup^T + m_bup
    gemm_bias_big<<<dim3(512/64, MROWS_/64), 256, 0, stream>>>(r, m_Wup, m_bup, nullptr, up, MROWS_, 512, 128);
    // 3. FUSED conv+silu + q/k/v headwise + gateproj
    mlstm_qkv<<<MROWS_, 64, 0, stream>>>(up, m_convk, m_convb, m_Wq, m_bq, m_Wk, m_bk,
                                         m_Wv, m_bv, m_Wig, m_big, m_Wfg, m_bfg,
                                         xc, q, kbuf, vbuf, igp, fgp);
    // 4. decay precompute
    mlstm_scan_pre<<<B_*NH_, 1024, 0, stream>>>(igp, fgp, lc, av, mx);
    // 5. attention + fused mh-LN/skip/gate epilogue -> hs
    mlstm_attn_tiled<<<B_*NH_*16, 256, 0, stream>>>(q, kbuf, vbuf, lc, av, mx,
                                                    xc, up, m_onw, m_skip, hs);
    // 6. h += hs @ m_Wd^T + m_bd ; r = LN(h)*ln1_w
    gemm_ln<<<MROWS_/32, 256, 0, stream>>>(hs, m_Wd, m_bd, h, ln1_w, h, r, MROWS_, 256);
    // 7. FUSED sLSTM conv+silu + 4-gate matvecs
    slstm_convgates<<<MROWS_, 128, 0, stream>>>(r, s_convk, s_convb, s_Wi, s_Wf, s_Wz, s_Wo, gx);
    // 8. sequential scan
    slstm_scan_wave<<<B_*NH_, 64, 0, stream>>>(gx, s_R, s_b, ys);
    // 9. FUSED h += mh_ln(ys)*gnw ; r = LN(h)*ffn_nw
    slstm_addnorm_ln<<<MROWS_, 128, 0, stream>>>(ys, s_gnw, ffn_nw, h, r);
    // 10. FUSED FFN up-GEMM + gelu(g)*u2 -> act
    gemm_ffn_act<<<dim3(3, MROWS_/64), 256, 0, stream>>>(r, f_Wu, f_bu, act, MROWS_);
    // 11. h += act @ f_Wd^T + f_bd
    gemm_bias_big<<<dim3(128/64, MROWS_/64), 256, 0, stream>>>(act, f_Wd, f_bd, h, h, MROWS_, 128, 192);
    // 12. FUSED final LN (last token only) + FC
    final_ln_fc<<<B_, 128, 0, stream>>>(h, post_w, fc_W, fc_b, out);
    (void)in_sizes; (void)n_in; (void)out_size; (void)ws_size;
}